// Round 1
// baseline (507.237 us; speedup 1.0000x reference)
//
#include <hip/hip_runtime.h>
#include <math.h>

#define B_ 8
#define L_ 4096
#define DM 128
#define DI 256
#define DSN 16
#define RK 8
#define M_ (B_*L_)      // 32768 positions
#define NC 64           // number of scan chunks
#define CH 64           // chunk length (NC*CH == L_)

__device__ __forceinline__ float silu_f(float x) { return x / (1.f + __expf(-x)); }

// ---------------------------------------------------------------------------
// C[m,n] = sum_k A[m*lda + k] * W[n*K + k]   (A: M x K strided, W: N x K row-major)
// 64x64 tile, BK=16, 256 threads, 4x4 micro-tile per thread, float4 LDS reads.
// ---------------------------------------------------------------------------
__global__ __launch_bounds__(256)
void gemm_nt(const float* __restrict__ A, int lda,
             const float* __restrict__ W,
             float* __restrict__ C, int ldc,
             int K) {
  __shared__ float As[16][68];   // [k][m], pad keeps 16B alignment + conflict-free
  __shared__ float Ws[16][68];   // [k][n]
  const int t  = threadIdx.x;
  const int tx = t & 15, ty = t >> 4;
  const int m0 = blockIdx.y << 6, n0 = blockIdx.x << 6;
  const int lr = t >> 2, lk = (t & 3) << 2;   // loader: row lr (0..63), k-offset lk (0,4,8,12)
  float acc[4][4] = {};
  const float* Ap = A + (m0 + lr) * lda + lk;
  const float* Wp = W + (n0 + lr) * K + lk;
  for (int k0 = 0; k0 < K; k0 += 16) {
    float4 av = *(const float4*)(Ap + k0);
    float4 wv = *(const float4*)(Wp + k0);
    __syncthreads();
    As[lk+0][lr] = av.x; As[lk+1][lr] = av.y; As[lk+2][lr] = av.z; As[lk+3][lr] = av.w;
    Ws[lk+0][lr] = wv.x; Ws[lk+1][lr] = wv.y; Ws[lk+2][lr] = wv.z; Ws[lk+3][lr] = wv.w;
    __syncthreads();
#pragma unroll
    for (int k = 0; k < 16; ++k) {
      float4 a4 = *(const float4*)&As[k][ty << 2];
      float4 w4 = *(const float4*)&Ws[k][tx << 2];
      float ar[4] = {a4.x, a4.y, a4.z, a4.w};
      float wr[4] = {w4.x, w4.y, w4.z, w4.w};
#pragma unroll
      for (int r = 0; r < 4; ++r)
#pragma unroll
        for (int c = 0; c < 4; ++c)
          acc[r][c] = fmaf(ar[r], wr[c], acc[r][c]);
    }
  }
#pragma unroll
  for (int r = 0; r < 4; ++r) {
    float4 o4 = make_float4(acc[r][0], acc[r][1], acc[r][2], acc[r][3]);
    *(float4*)&C[(m0 + (ty << 2) + r) * ldc + n0 + (tx << 2)] = o4;
  }
}

// ---------------------------------------------------------------------------
// Depthwise causal conv(4) + bias + SiLU over the x half of xz (B,L,512).
// ---------------------------------------------------------------------------
__global__ __launch_bounds__(256)
void conv_silu_k(const float* __restrict__ xz, const float* __restrict__ cw,
                 const float* __restrict__ cb, float* __restrict__ xact) {
  int idx = blockIdx.x * 256 + threadIdx.x;   // over M_*256
  int d = idx & 255, m = idx >> 8, l = m & (L_ - 1);
  float acc = cb[d];
#pragma unroll
  for (int j = 0; j < 4; ++j) {
    int ls = l - 3 + j;
    float v = (ls >= 0) ? xz[(m - 3 + j) * 512 + d] : 0.f;
    acc = fmaf(cw[d * 4 + j], v, acc);
  }
  xact[idx] = silu_f(acc);
}

// ---------------------------------------------------------------------------
// x_dbl = x_act @ x_proj_w^T (40 outs); dt_full = softplus(x_dbl[:,:8] @ dt_proj_w^T + b)
// 32 positions per block, 256 threads.
// ---------------------------------------------------------------------------
__global__ __launch_bounds__(256)
void xproj_dtproj(const float* __restrict__ xact, const float* __restrict__ xw,
                  const float* __restrict__ dtw, const float* __restrict__ dtb,
                  float* __restrict__ xdbl, float* __restrict__ dtf) {
  __shared__ float xa[32 * 257];     // activations, padded (stride 257 -> conflict-free)
  __shared__ float wdt[256 * 9];     // dt_proj_w padded
  __shared__ float dtr[32 * 8];      // dt_rank intermediates
  const int t = threadIdx.x;
  const int p0 = blockIdx.x << 5;
  for (int i = t; i < 256 * 8; i += 256) wdt[(i >> 3) * 9 + (i & 7)] = dtw[i];
  for (int i = t; i < 32 * 256; i += 256) {
    int p = i >> 8, k = i & 255;
    xa[p * 257 + k] = xact[(p0 + p) * 256 + k];
  }
  __syncthreads();
  // phase A: each thread: one position p, 5 outputs (g*5..g*5+4)
  const int p = t & 31, g = t >> 5;
  float acc[5] = {0, 0, 0, 0, 0};
  for (int k = 0; k < 256; ++k) {
    float xv = xa[p * 257 + k];
#pragma unroll
    for (int j = 0; j < 5; ++j) acc[j] = fmaf(xv, xw[(g * 5 + j) * 256 + k], acc[j]);
  }
#pragma unroll
  for (int j = 0; j < 5; ++j) {
    int o = g * 5 + j;
    xdbl[(p0 + p) * 40 + o] = acc[j];
    if (o < RK) dtr[p * 8 + o] = acc[j];
  }
  __syncthreads();
  // phase B: dt projection + softplus
  for (int i = t; i < 32 * 256; i += 256) {
    int pp = i >> 8, d = i & 255;
    float a2 = dtb[d];
#pragma unroll
    for (int r2 = 0; r2 < RK; ++r2) a2 = fmaf(dtr[pp * 8 + r2], wdt[d * 9 + r2], a2);
    float sp = (a2 > 20.f) ? a2 : log1pf(__expf(a2));
    dtf[(p0 + pp) * 256 + d] = sp;
  }
}

// ---------------------------------------------------------------------------
// Scan phase 1: per (b, chunk, 16-channel group) compute transfer P = prod dA
// and h_end (h0 = 0). Lane = (state s, channel-quad dq); block = 16 channels.
// ---------------------------------------------------------------------------
__global__ __launch_bounds__(256)
void scan_phase1(const float* __restrict__ dtf, const float* __restrict__ uact,
                 const float* __restrict__ xdbl, const float* __restrict__ alog,
                 float* __restrict__ cP, float* __restrict__ cHe) {
  __shared__ float dt_s[CH * 16], u_s[CH * 16], b_s[CH * 16];
  const int blk = blockIdx.x;
  const int b = blk >> 10;          // / (NC*16)
  const int r = blk & 1023;
  const int c = r >> 4;
  const int d0 = (r & 15) << 4;
  const int t = threadIdx.x;
  const int l0 = c << 6;
  {
    int ll = t >> 2, j = (t & 3) << 2;
    int gb = b * L_ + l0 + ll;
    *(float4*)&dt_s[ll * 16 + j] = *(const float4*)&dtf[gb * 256 + d0 + j];
    *(float4*)&u_s[ll * 16 + j]  = *(const float4*)&uact[gb * 256 + d0 + j];
    *(float4*)&b_s[ll * 16 + j]  = *(const float4*)&xdbl[gb * 40 + 8 + j];
  }
  __syncthreads();
  const int lane = t & 63, w = t >> 6;
  const int s = lane & 15, dq = lane >> 4;
  const int dloc = (w << 2) + dq;
  const float a = -__expf(alog[(d0 + dloc) * 16 + s]);
  float h = 0.f, P = 1.f;
  for (int ll = 0; ll < CH; ++ll) {
    float dtv = dt_s[ll * 16 + dloc];
    float uv  = u_s[ll * 16 + dloc];
    float bv  = b_s[ll * 16 + s];
    float dA = __expf(dtv * a);
    h = fmaf(dA, h, dtv * uv * bv);
    P *= dA;
  }
  int o = ((b * NC + c) * 256 + d0 + dloc) * 16 + s;
  cP[o] = P;
  cHe[o] = h;
}

// ---------------------------------------------------------------------------
// Scan phase 2: serial stitch over chunks for each (b,d,s).
// ---------------------------------------------------------------------------
__global__ __launch_bounds__(256)
void scan_combine(const float* __restrict__ cP, const float* __restrict__ cHe,
                  float* __restrict__ hst) {
  int tid = blockIdx.x * 256 + threadIdx.x;   // < 8*256*16 = 32768
  int b = tid >> 12;
  int ds = tid & 4095;                        // d*16 + s
  float hs = 0.f;
  for (int c = 0; c < NC; ++c) {
    int idx = (b * NC + c) * 4096 + ds;
    hst[idx] = hs;
    hs = fmaf(cP[idx], hs, cHe[idx]);
  }
}

// ---------------------------------------------------------------------------
// Scan phase 3: replay chunk from true h_start, emit y, + u*D_skip, * silu(z).
// Writes gated y in-place over the z half of xz.
// ---------------------------------------------------------------------------
__global__ __launch_bounds__(256)
void scan_phase3(const float* __restrict__ dtf, const float* __restrict__ uact,
                 const float* __restrict__ xdbl, const float* __restrict__ alog,
                 const float* __restrict__ hst, const float* __restrict__ dsk,
                 float* __restrict__ xz) {
  __shared__ float dt_s[CH * 16], u_s[CH * 16], b_s[CH * 16], c_s[CH * 16], y_s[CH * 16];
  const int blk = blockIdx.x;
  const int b = blk >> 10;
  const int r = blk & 1023;
  const int c = r >> 4;
  const int d0 = (r & 15) << 4;
  const int t = threadIdx.x;
  const int l0 = c << 6;
  {
    int ll = t >> 2, j = (t & 3) << 2;
    int gb = b * L_ + l0 + ll;
    *(float4*)&dt_s[ll * 16 + j] = *(const float4*)&dtf[gb * 256 + d0 + j];
    *(float4*)&u_s[ll * 16 + j]  = *(const float4*)&uact[gb * 256 + d0 + j];
    *(float4*)&b_s[ll * 16 + j]  = *(const float4*)&xdbl[gb * 40 + 8 + j];
    *(float4*)&c_s[ll * 16 + j]  = *(const float4*)&xdbl[gb * 40 + 24 + j];
  }
  __syncthreads();
  const int lane = t & 63, w = t >> 6;
  const int s = lane & 15, dq = lane >> 4;
  const int dloc = (w << 2) + dq;
  const float a = -__expf(alog[(d0 + dloc) * 16 + s]);
  float h = hst[((b * NC + c) * 256 + d0 + dloc) * 16 + s];
  for (int ll = 0; ll < CH; ++ll) {
    float dtv = dt_s[ll * 16 + dloc];
    float uv  = u_s[ll * 16 + dloc];
    float bv  = b_s[ll * 16 + s];
    float dA = __expf(dtv * a);
    h = fmaf(dA, h, dtv * uv * bv);
    float yc = h * c_s[ll * 16 + s];
    yc += __shfl_xor(yc, 1);
    yc += __shfl_xor(yc, 2);
    yc += __shfl_xor(yc, 4);
    yc += __shfl_xor(yc, 8);
    if (s == 0) y_s[ll * 16 + dloc] = yc;
  }
  __syncthreads();
  {
    int ll = t >> 2, j = (t & 3) << 2;
    int m = b * L_ + l0 + ll;
    float4 yv = *(float4*)&y_s[ll * 16 + j];
    float4 uv = *(float4*)&u_s[ll * 16 + j];
    int zi = m * 512 + 256 + d0 + j;
    float4 zv = *(const float4*)&xz[zi];
    float4 o4;
    o4.x = (yv.x + uv.x * dsk[d0 + j + 0]) * silu_f(zv.x);
    o4.y = (yv.y + uv.y * dsk[d0 + j + 1]) * silu_f(zv.y);
    o4.z = (yv.z + uv.z * dsk[d0 + j + 2]) * silu_f(zv.z);
    o4.w = (yv.w + uv.w * dsk[d0 + j + 3]) * silu_f(zv.w);
    *(float4*)&xz[zi] = o4;
  }
}

// ---------------------------------------------------------------------------
// LayerNorm(128) + fc(128x128) + ReLU. 128 threads, 16 positions/block.
// fc weight row per output channel lives in registers (reused 16x).
// ---------------------------------------------------------------------------
__global__ __launch_bounds__(128)
void ln_fc_relu(const float* __restrict__ Hin, const float* __restrict__ gamma,
                const float* __restrict__ beta, const float* __restrict__ fcw,
                float* __restrict__ out) {
  __shared__ float hn[DM];
  __shared__ float cwred[4];
  const int t = threadIdx.x;
  float wreg[DM];
#pragma unroll
  for (int k = 0; k < DM; ++k) wreg[k] = fcw[t * DM + k];
  const float g = gamma[t], be = beta[t];
  const int m0 = blockIdx.x * 16;
  for (int p = 0; p < 16; ++p) {
    const int m = m0 + p;
    float v = Hin[m * DM + t];
    float s1 = v, s2 = v * v;
#pragma unroll
    for (int msk = 1; msk < 64; msk <<= 1) {
      s1 += __shfl_xor(s1, msk);
      s2 += __shfl_xor(s2, msk);
    }
    if ((t & 63) == 0) { cwred[(t >> 6) * 2] = s1; cwred[(t >> 6) * 2 + 1] = s2; }
    __syncthreads();
    float S1 = cwred[0] + cwred[2], S2 = cwred[1] + cwred[3];
    float mu = S1 * (1.f / DM);
    float var = S2 * (1.f / DM) - mu * mu;
    float rs = rsqrtf(var + 1e-5f);
    hn[t] = (v - mu) * rs * g + be;
    __syncthreads();
    float acc = 0.f;
#pragma unroll
    for (int k = 0; k < DM; ++k) acc = fmaf(hn[k], wreg[k], acc);
    out[m * DM + t] = fmaxf(acc, 0.f);
    __syncthreads();
  }
}

extern "C" void kernel_launch(void* const* d_in, const int* in_sizes, int n_in,
                              void* d_out, int out_size, void* d_ws, size_t ws_size,
                              hipStream_t stream) {
  (void)in_sizes; (void)n_in; (void)out_size; (void)ws_size;
  const float* s    = (const float*)d_in[0];
  const float* w_in = (const float*)d_in[1];
  const float* cw   = (const float*)d_in[2];
  const float* cb   = (const float*)d_in[3];
  const float* xw   = (const float*)d_in[4];
  const float* dtw  = (const float*)d_in[5];
  const float* dtb  = (const float*)d_in[6];
  const float* alog = (const float*)d_in[7];
  const float* dsk  = (const float*)d_in[8];
  const float* ow   = (const float*)d_in[9];
  const float* gam  = (const float*)d_in[10];
  const float* bet  = (const float*)d_in[11];
  const float* fcw  = (const float*)d_in[12];
  float* out = (float*)d_out;
  float* ws  = (float*)d_ws;

  float* xz   = ws;                      // M*512  (x | z; z half later holds gated y)
  float* xact = ws + 16777216;           // M*256  (u = silu(conv(x)))
  float* xdbl = ws + 25165824;           // M*40   (dt_r | B | C)
  float* dtf  = ws + 26476544;           // M*256  (softplus dt)
  float* cP   = ws + 34865152;           // B*NC*256*16
  float* cHe  = ws + 36962304;           // B*NC*256*16
  float* hst  = ws + 39059456;           // B*NC*256*16
  float* hmid = cP;                      // M*128, aliases cP+cHe (dead after phase 3)

  // 1. in_proj: xz = s @ W_in^T   (M x 512)
  gemm_nt<<<dim3(8, 512), 256, 0, stream>>>(s, 128, w_in, xz, 512, 128);
  // 2. causal depthwise conv + SiLU -> xact
  conv_silu_k<<<32768, 256, 0, stream>>>(xz, cw, cb, xact);
  // 3. x_proj + dt_proj + softplus
  xproj_dtproj<<<1024, 256, 0, stream>>>(xact, xw, dtw, dtb, xdbl, dtf);
  // 4-6. chunked selective scan
  scan_phase1<<<8192, 256, 0, stream>>>(dtf, xact, xdbl, alog, cP, cHe);
  scan_combine<<<128, 256, 0, stream>>>(cP, cHe, hst);
  scan_phase3<<<8192, 256, 0, stream>>>(dtf, xact, xdbl, alog, hst, dsk, xz);
  // 7. out_proj: hmid = y_gated @ out_proj_w^T  (y_gated = z half of xz, lda 512)
  gemm_nt<<<dim3(2, 512), 256, 0, stream>>>(xz + 256, 512, ow, hmid, 128, 256);
  // 8. LayerNorm + fc + ReLU
  ln_fc_relu<<<2048, 128, 0, stream>>>(hmid, gam, bet, fcw, out);
}

// Round 2
// 439.821 us; speedup vs baseline: 1.1533x; 1.1533x over previous
//
#include <hip/hip_runtime.h>
#include <math.h>

#define B_ 8
#define L_ 4096
#define DM 128
#define DI 256
#define DSN 16
#define RK 8
#define M_ (B_*L_)      // 32768 positions
#define NC 128          // number of scan chunks
#define CH 32           // chunk length (NC*CH == L_)

__device__ __forceinline__ float silu_f(float x) { return x / (1.f + __expf(-x)); }

// ---------------------------------------------------------------------------
// C[m,n] = sum_k A[m*lda + k] * W[n*K + k]   (A: M x K strided, W: N x K row-major)
// 64x64 tile, BK=16, 256 threads, 4x4 micro-tile per thread, float4 LDS reads.
// ---------------------------------------------------------------------------
__global__ __launch_bounds__(256)
void gemm_nt(const float* __restrict__ A, int lda,
             const float* __restrict__ W,
             float* __restrict__ C, int ldc,
             int K) {
  __shared__ float As[16][68];
  __shared__ float Ws[16][68];
  const int t  = threadIdx.x;
  const int tx = t & 15, ty = t >> 4;
  const int m0 = blockIdx.y << 6, n0 = blockIdx.x << 6;
  const int lr = t >> 2, lk = (t & 3) << 2;
  float acc[4][4] = {};
  const float* Ap = A + (m0 + lr) * lda + lk;
  const float* Wp = W + (n0 + lr) * K + lk;
  for (int k0 = 0; k0 < K; k0 += 16) {
    float4 av = *(const float4*)(Ap + k0);
    float4 wv = *(const float4*)(Wp + k0);
    __syncthreads();
    As[lk+0][lr] = av.x; As[lk+1][lr] = av.y; As[lk+2][lr] = av.z; As[lk+3][lr] = av.w;
    Ws[lk+0][lr] = wv.x; Ws[lk+1][lr] = wv.y; Ws[lk+2][lr] = wv.z; Ws[lk+3][lr] = wv.w;
    __syncthreads();
#pragma unroll
    for (int k = 0; k < 16; ++k) {
      float4 a4 = *(const float4*)&As[k][ty << 2];
      float4 w4 = *(const float4*)&Ws[k][tx << 2];
      float ar[4] = {a4.x, a4.y, a4.z, a4.w};
      float wr[4] = {w4.x, w4.y, w4.z, w4.w};
#pragma unroll
      for (int r = 0; r < 4; ++r)
#pragma unroll
        for (int c = 0; c < 4; ++c)
          acc[r][c] = fmaf(ar[r], wr[c], acc[r][c]);
    }
  }
#pragma unroll
  for (int r = 0; r < 4; ++r) {
    float4 o4 = make_float4(acc[r][0], acc[r][1], acc[r][2], acc[r][3]);
    *(float4*)&C[(m0 + (ty << 2) + r) * ldc + n0 + (tx << 2)] = o4;
  }
}

// ---------------------------------------------------------------------------
// Fused conv(4)+SiLU staging + x_proj + dt_proj + softplus.
// u is recomputed on the fly from the x half of xz (no xact buffer).
// Outputs: Bb (M x 16), Cb (M x 16), dtf (M x 256).
// ---------------------------------------------------------------------------
__global__ __launch_bounds__(256)
void xproj_dtproj(const float* __restrict__ xz, const float* __restrict__ xw,
                  const float* __restrict__ dtw, const float* __restrict__ dtb,
                  const float* __restrict__ cw, const float* __restrict__ cb,
                  float* __restrict__ Bb, float* __restrict__ Cb,
                  float* __restrict__ dtf) {
  __shared__ float xa[32 * 257];
  __shared__ float wdt[256 * 9];
  __shared__ float dtr[32 * 8];
  const int t = threadIdx.x;
  const int p0 = blockIdx.x << 5;
  for (int i = t; i < 256 * 8; i += 256) wdt[(i >> 3) * 9 + (i & 7)] = dtw[i];
  // stage u = silu(conv(x)) for 32 positions x 256 channels
  for (int i = t; i < 32 * 256; i += 256) {
    int p = i >> 8, k = i & 255;
    int m = p0 + p, l = m & (L_ - 1);
    float acc = cb[k];
#pragma unroll
    for (int j = 0; j < 4; ++j) {
      int ls = l - 3 + j;
      float v = (ls >= 0) ? xz[(m - 3 + j) * 512 + k] : 0.f;
      acc = fmaf(cw[k * 4 + j], v, acc);
    }
    xa[p * 257 + k] = silu_f(acc);
  }
  __syncthreads();
  // phase A: thread -> one position p, 5 outputs
  const int p = t & 31, g = t >> 5;
  float acc[5] = {0, 0, 0, 0, 0};
  for (int k = 0; k < 256; ++k) {
    float xv = xa[p * 257 + k];
#pragma unroll
    for (int j = 0; j < 5; ++j) acc[j] = fmaf(xv, xw[(g * 5 + j) * 256 + k], acc[j]);
  }
#pragma unroll
  for (int j = 0; j < 5; ++j) {
    int o = g * 5 + j;
    if (o < RK)       dtr[p * 8 + o] = acc[j];
    else if (o < 24)  Bb[(p0 + p) * 16 + (o - 8)]  = acc[j];
    else              Cb[(p0 + p) * 16 + (o - 24)] = acc[j];
  }
  __syncthreads();
  // phase B: dt projection + softplus
  for (int i = t; i < 32 * 256; i += 256) {
    int pp = i >> 8, d = i & 255;
    float a2 = dtb[d];
#pragma unroll
    for (int r2 = 0; r2 < RK; ++r2) a2 = fmaf(dtr[pp * 8 + r2], wdt[d * 9 + r2], a2);
    float sp = (a2 > 20.f) ? a2 : log1pf(__expf(a2));
    dtf[(p0 + pp) * 256 + d] = sp;
  }
}

// ---------------------------------------------------------------------------
// Scan phase 1: thread = channel d, all 16 states in registers. One block per
// (b, chunk). u recomputed via register-shift conv. B is wave-uniform -> SMEM.
// Outputs cP/cHe layout [(b*NC+c), s, d].
// ---------------------------------------------------------------------------
__global__ __launch_bounds__(256, 4)
void scan_phase1(const float* __restrict__ xz, const float* __restrict__ dtf,
                 const float* __restrict__ Bb, const float* __restrict__ alog,
                 const float* __restrict__ cw, const float* __restrict__ cb,
                 float* __restrict__ cP, float* __restrict__ cHe) {
  const int bc = blockIdx.x;            // b*NC + c
  const int b = bc >> 7, c = bc & (NC - 1);
  const int d = threadIdx.x;
  const int l0 = c * CH;
  const int base = b * L_ + l0;
  float a[16];
#pragma unroll
  for (int s4 = 0; s4 < 4; ++s4) {
    float4 v = *(const float4*)&alog[d * 16 + s4 * 4];
    a[s4*4+0] = -__expf(v.x); a[s4*4+1] = -__expf(v.y);
    a[s4*4+2] = -__expf(v.z); a[s4*4+3] = -__expf(v.w);
  }
  const float w0 = cw[d*4], w1 = cw[d*4+1], w2 = cw[d*4+2], w3 = cw[d*4+3];
  const float bias = cb[d];
  float x0 = (l0 >= 3) ? xz[(base - 3) * 512 + d] : 0.f;
  float x1 = (l0 >= 2) ? xz[(base - 2) * 512 + d] : 0.f;
  float x2 = (l0 >= 1) ? xz[(base - 1) * 512 + d] : 0.f;
  float h[16], P[16];
#pragma unroll
  for (int s = 0; s < 16; ++s) { h[s] = 0.f; P[s] = 1.f; }
  for (int l = 0; l < CH; ++l) {
    const int m = base + l;
    float x3  = xz[m * 512 + d];
    float dtv = dtf[m * 256 + d];
    const float4* Bp = (const float4*)&Bb[m * 16];
    float Bv[16];
    *(float4*)&Bv[0] = Bp[0]; *(float4*)&Bv[4]  = Bp[1];
    *(float4*)&Bv[8] = Bp[2]; *(float4*)&Bv[12] = Bp[3];
    float u = silu_f(fmaf(w0, x0, fmaf(w1, x1, fmaf(w2, x2, fmaf(w3, x3, bias)))));
    float du = dtv * u;
#pragma unroll
    for (int s = 0; s < 16; ++s) {
      float dA = __expf(dtv * a[s]);
      P[s] *= dA;
      h[s] = fmaf(dA, h[s], du * Bv[s]);
    }
    x0 = x1; x1 = x2; x2 = x3;
  }
#pragma unroll
  for (int s = 0; s < 16; ++s) {
    cP[(bc * 16 + s) * 256 + d]  = P[s];
    cHe[(bc * 16 + s) * 256 + d] = h[s];
  }
}

// ---------------------------------------------------------------------------
// Scan phase 2: serial stitch over chunks; h_start overwrites cP in place.
// ---------------------------------------------------------------------------
__global__ __launch_bounds__(256)
void scan_combine(float* __restrict__ cP, const float* __restrict__ cHe) {
  int tid = blockIdx.x * 256 + threadIdx.x;   // < 8*4096
  int b = tid >> 12;
  int sd = tid & 4095;                        // s*256 + d
  float hs = 0.f;
  for (int c = 0; c < NC; ++c) {
    int idx = (b * NC + c) * 4096 + sd;
    float p = cP[idx];
    float he = cHe[idx];
    cP[idx] = hs;                              // h_start for this chunk
    hs = fmaf(p, hs, he);
  }
}

// ---------------------------------------------------------------------------
// Scan phase 3: replay chunk from true h_start, y = h.C in registers,
// + u*D_skip, * silu(z); writes gated y over the z half of xz.
// ---------------------------------------------------------------------------
__global__ __launch_bounds__(256, 4)
void scan_phase3(const float* __restrict__ dtf,
                 const float* __restrict__ Bb, const float* __restrict__ Cb,
                 const float* __restrict__ alog,
                 const float* __restrict__ cw, const float* __restrict__ cb,
                 const float* __restrict__ hst, const float* __restrict__ dsk,
                 float* __restrict__ xz) {
  const int bc = blockIdx.x;
  const int b = bc >> 7, c = bc & (NC - 1);
  const int d = threadIdx.x;
  const int l0 = c * CH;
  const int base = b * L_ + l0;
  float a[16];
#pragma unroll
  for (int s4 = 0; s4 < 4; ++s4) {
    float4 v = *(const float4*)&alog[d * 16 + s4 * 4];
    a[s4*4+0] = -__expf(v.x); a[s4*4+1] = -__expf(v.y);
    a[s4*4+2] = -__expf(v.z); a[s4*4+3] = -__expf(v.w);
  }
  const float w0 = cw[d*4], w1 = cw[d*4+1], w2 = cw[d*4+2], w3 = cw[d*4+3];
  const float bias = cb[d];
  const float dskv = dsk[d];
  float x0 = (l0 >= 3) ? xz[(base - 3) * 512 + d] : 0.f;
  float x1 = (l0 >= 2) ? xz[(base - 2) * 512 + d] : 0.f;
  float x2 = (l0 >= 1) ? xz[(base - 1) * 512 + d] : 0.f;
  float h[16];
#pragma unroll
  for (int s = 0; s < 16; ++s) h[s] = hst[(bc * 16 + s) * 256 + d];
  for (int l = 0; l < CH; ++l) {
    const int m = base + l;
    float x3  = xz[m * 512 + d];
    float dtv = dtf[m * 256 + d];
    float zv  = xz[m * 512 + 256 + d];
    const float4* Bp = (const float4*)&Bb[m * 16];
    const float4* Cp = (const float4*)&Cb[m * 16];
    float Bv[16], Cv[16];
    *(float4*)&Bv[0] = Bp[0]; *(float4*)&Bv[4]  = Bp[1];
    *(float4*)&Bv[8] = Bp[2]; *(float4*)&Bv[12] = Bp[3];
    *(float4*)&Cv[0] = Cp[0]; *(float4*)&Cv[4]  = Cp[1];
    *(float4*)&Cv[8] = Cp[2]; *(float4*)&Cv[12] = Cp[3];
    float u = silu_f(fmaf(w0, x0, fmaf(w1, x1, fmaf(w2, x2, fmaf(w3, x3, bias)))));
    float du = dtv * u;
    float y = 0.f;
#pragma unroll
    for (int s = 0; s < 16; ++s) {
      float dA = __expf(dtv * a[s]);
      h[s] = fmaf(dA, h[s], du * Bv[s]);
      y = fmaf(h[s], Cv[s], y);
    }
    xz[m * 512 + 256 + d] = (y + u * dskv) * silu_f(zv);
    x0 = x1; x1 = x2; x2 = x3;
  }
}

// ---------------------------------------------------------------------------
// LayerNorm(128) + fc(128x128) + ReLU. 128 threads, 16 positions/block.
// ---------------------------------------------------------------------------
__global__ __launch_bounds__(128)
void ln_fc_relu(const float* __restrict__ Hin, const float* __restrict__ gamma,
                const float* __restrict__ beta, const float* __restrict__ fcw,
                float* __restrict__ out) {
  __shared__ float hn[DM];
  __shared__ float cwred[4];
  const int t = threadIdx.x;
  float wreg[DM];
#pragma unroll
  for (int k = 0; k < DM; ++k) wreg[k] = fcw[t * DM + k];
  const float g = gamma[t], be = beta[t];
  const int m0 = blockIdx.x * 16;
  for (int p = 0; p < 16; ++p) {
    const int m = m0 + p;
    float v = Hin[m * DM + t];
    float s1 = v, s2 = v * v;
#pragma unroll
    for (int msk = 1; msk < 64; msk <<= 1) {
      s1 += __shfl_xor(s1, msk);
      s2 += __shfl_xor(s2, msk);
    }
    if ((t & 63) == 0) { cwred[(t >> 6) * 2] = s1; cwred[(t >> 6) * 2 + 1] = s2; }
    __syncthreads();
    float S1 = cwred[0] + cwred[2], S2 = cwred[1] + cwred[3];
    float mu = S1 * (1.f / DM);
    float var = S2 * (1.f / DM) - mu * mu;
    float rs = rsqrtf(var + 1e-5f);
    hn[t] = (v - mu) * rs * g + be;
    __syncthreads();
    float acc = 0.f;
#pragma unroll
    for (int k = 0; k < DM; ++k) acc = fmaf(hn[k], wreg[k], acc);
    out[m * DM + t] = fmaxf(acc, 0.f);
    __syncthreads();
  }
}

extern "C" void kernel_launch(void* const* d_in, const int* in_sizes, int n_in,
                              void* d_out, int out_size, void* d_ws, size_t ws_size,
                              hipStream_t stream) {
  (void)in_sizes; (void)n_in; (void)out_size; (void)ws_size;
  const float* s    = (const float*)d_in[0];
  const float* w_in = (const float*)d_in[1];
  const float* cw   = (const float*)d_in[2];
  const float* cb   = (const float*)d_in[3];
  const float* xw   = (const float*)d_in[4];
  const float* dtw  = (const float*)d_in[5];
  const float* dtb  = (const float*)d_in[6];
  const float* alog = (const float*)d_in[7];
  const float* dsk  = (const float*)d_in[8];
  const float* ow   = (const float*)d_in[9];
  const float* gam  = (const float*)d_in[10];
  const float* bet  = (const float*)d_in[11];
  const float* fcw  = (const float*)d_in[12];
  float* out = (float*)d_out;
  float* ws  = (float*)d_ws;

  float* xz   = ws;                      // M*512  (x | z; z half later holds gated y)
  float* dtf  = ws + 16777216;           // M*256
  float* Bb   = ws + 25165824;           // M*16
  float* Cb   = ws + 25690112;           // M*16
  float* cP   = ws + 26214400;           // B*NC*4096  (later: h_start, then hmid)
  float* cHe  = ws + 30408704;           // B*NC*4096
  float* hmid = cP;                      // M*128, aliases cP (dead after phase 3)

  // 1. in_proj: xz = s @ W_in^T   (M x 512)
  gemm_nt<<<dim3(8, 512), 256, 0, stream>>>(s, 128, w_in, xz, 512, 128);
  // 2. fused conv/silu + x_proj + dt_proj
  xproj_dtproj<<<1024, 256, 0, stream>>>(xz, xw, dtw, dtb, cw, cb, Bb, Cb, dtf);
  // 3-5. chunked selective scan (register-state formulation)
  scan_phase1<<<B_ * NC, 256, 0, stream>>>(xz, dtf, Bb, alog, cw, cb, cP, cHe);
  scan_combine<<<128, 256, 0, stream>>>(cP, cHe);
  scan_phase3<<<B_ * NC, 256, 0, stream>>>(dtf, Bb, Cb, alog, cw, cb, cP, dsk, xz);
  // 6. out_proj: hmid = y_gated @ out_proj_w^T
  gemm_nt<<<dim3(2, 512), 256, 0, stream>>>(xz + 256, 512, ow, hmid, 128, 256);
  // 7. LayerNorm + fc + ReLU
  ln_fc_relu<<<2048, 128, 0, stream>>>(hmid, gam, bet, fcw, out);
}

// Round 3
// 419.577 us; speedup vs baseline: 1.2089x; 1.0482x over previous
//
#include <hip/hip_runtime.h>
#include <math.h>

#define B_ 8
#define L_ 4096
#define DM 128
#define DI 256
#define DSN 16
#define RK 8
#define M_ (B_*L_)      // 32768 positions
#define NC 128          // number of scan chunks
#define CH 32           // chunk length (NC*CH == L_)

__device__ __forceinline__ float silu_f(float x) { return x / (1.f + __expf(-x)); }

// ---------------------------------------------------------------------------
// C[m,n] = sum_k A[m*lda + k] * W[n*K + k]   (A: M x K strided, W: N x K row-major)
// 64x64 tile, BK=16, 256 threads, 4x4 micro-tile per thread, float4 LDS reads.
// ---------------------------------------------------------------------------
__global__ __launch_bounds__(256)
void gemm_nt(const float* __restrict__ A, int lda,
             const float* __restrict__ W,
             float* __restrict__ C, int ldc,
             int K) {
  __shared__ float As[16][68];
  __shared__ float Ws[16][68];
  const int t  = threadIdx.x;
  const int tx = t & 15, ty = t >> 4;
  const int m0 = blockIdx.y << 6, n0 = blockIdx.x << 6;
  const int lr = t >> 2, lk = (t & 3) << 2;
  float acc[4][4] = {};
  const float* Ap = A + (m0 + lr) * lda + lk;
  const float* Wp = W + (n0 + lr) * K + lk;
  for (int k0 = 0; k0 < K; k0 += 16) {
    float4 av = *(const float4*)(Ap + k0);
    float4 wv = *(const float4*)(Wp + k0);
    __syncthreads();
    As[lk+0][lr] = av.x; As[lk+1][lr] = av.y; As[lk+2][lr] = av.z; As[lk+3][lr] = av.w;
    Ws[lk+0][lr] = wv.x; Ws[lk+1][lr] = wv.y; Ws[lk+2][lr] = wv.z; Ws[lk+3][lr] = wv.w;
    __syncthreads();
#pragma unroll
    for (int k = 0; k < 16; ++k) {
      float4 a4 = *(const float4*)&As[k][ty << 2];
      float4 w4 = *(const float4*)&Ws[k][tx << 2];
      float ar[4] = {a4.x, a4.y, a4.z, a4.w};
      float wr[4] = {w4.x, w4.y, w4.z, w4.w};
#pragma unroll
      for (int r = 0; r < 4; ++r)
#pragma unroll
        for (int c = 0; c < 4; ++c)
          acc[r][c] = fmaf(ar[r], wr[c], acc[r][c]);
    }
  }
#pragma unroll
  for (int r = 0; r < 4; ++r) {
    float4 o4 = make_float4(acc[r][0], acc[r][1], acc[r][2], acc[r][3]);
    *(float4*)&C[(m0 + (ty << 2) + r) * ldc + n0 + (tx << 2)] = o4;
  }
}

// ---------------------------------------------------------------------------
// Fused conv(4)+SiLU staging + x_proj + dt_proj + softplus.
// 64 positions/block. Phase A: lane = position, wave = output-group (g uniform
// via readfirstlane -> weight addresses scalar -> s_load on SMEM pipe).
// Outputs: Bb (M x 16), Cb (M x 16), dtf (M x 256).
// ---------------------------------------------------------------------------
__global__ __launch_bounds__(256)
void xproj_dtproj(const float* __restrict__ xz, const float* __restrict__ xw,
                  const float* __restrict__ dtw, const float* __restrict__ dtb,
                  const float* __restrict__ cw, const float* __restrict__ cb,
                  float* __restrict__ Bb, float* __restrict__ Cb,
                  float* __restrict__ dtf) {
  __shared__ float xa[64 * 257];   // u, [p][k], stride 257 -> bank-conflict-free
  __shared__ float dtr[64 * 12];   // x_proj outputs 0..7 per position (stride 12, 16B-aligned)
  const int t = threadIdx.x;
  const int p0 = blockIdx.x << 6;
  // stage u = silu(conv(x)): lanes over channels (coalesced)
  for (int i = t; i < 64 * 256; i += 256) {
    int p = i >> 8, k = i & 255;
    int m = p0 + p, l = m & (L_ - 1);
    float acc = cb[k];
#pragma unroll
    for (int j = 0; j < 4; ++j) {
      int ls = l - 3 + j;
      float v = (ls >= 0) ? xz[(m - 3 + j) * 512 + k] : 0.f;
      acc = fmaf(cw[k * 4 + j], v, acc);
    }
    xa[p * 257 + k] = silu_f(acc);
  }
  __syncthreads();
  // phase A: wave g computes outputs {5g..5g+4} and {20+5g..24+5g}, 64 positions
  const int p = t & 63;
  const int g = __builtin_amdgcn_readfirstlane(t >> 6);
  const float* wrow0 = xw + (g * 5) * 256;
  const float* wrow1 = xw + (20 + g * 5) * 256;
  float acc[10] = {};
  for (int k = 0; k < 256; ++k) {
    float xv = xa[p * 257 + k];
#pragma unroll
    for (int j = 0; j < 5; ++j) {
      acc[j]     = fmaf(xv, wrow0[j * 256 + k], acc[j]);
      acc[5 + j] = fmaf(xv, wrow1[j * 256 + k], acc[5 + j]);
    }
  }
  const int m = p0 + p;
#pragma unroll
  for (int j = 0; j < 5; ++j) {
    int o0 = g * 5 + j;        // 0..19
    int o1 = 20 + g * 5 + j;   // 20..39
    if (o0 < 8) dtr[p * 12 + o0] = acc[j];
    else        Bb[m * 16 + (o0 - 8)] = acc[j];
    if (o1 < 24) Bb[m * 16 + (o1 - 8)] = acc[5 + j];
    else         Cb[m * 16 + (o1 - 24)] = acc[5 + j];
  }
  __syncthreads();
  // phase B: thread = channel d; dt_proj weights in registers; dtr broadcast reads
  {
    const int d = t;
    float w8[8];
    *(float4*)&w8[0] = *(const float4*)&dtw[d * 8];
    *(float4*)&w8[4] = *(const float4*)&dtw[d * 8 + 4];
    const float bias = dtb[d];
    for (int pp = 0; pp < 64; ++pp) {
      float r0[8];
      *(float4*)&r0[0] = *(const float4*)&dtr[pp * 12];
      *(float4*)&r0[4] = *(const float4*)&dtr[pp * 12 + 4];
      float a2 = bias;
#pragma unroll
      for (int r2 = 0; r2 < 8; ++r2) a2 = fmaf(r0[r2], w8[r2], a2);
      float sp = (a2 > 20.f) ? a2 : log1pf(__expf(a2));
      dtf[(p0 + pp) * 256 + d] = sp;
    }
  }
}

// ---------------------------------------------------------------------------
// Scan phase 1: thread = channel d, all 16 states in registers. One block per
// (b, chunk). u recomputed via register-shift conv. B is wave-uniform reads.
// Outputs cP/cHe layout [(b*NC+c), s, d].
// ---------------------------------------------------------------------------
__global__ __launch_bounds__(256, 4)
void scan_phase1(const float* __restrict__ xz, const float* __restrict__ dtf,
                 const float* __restrict__ Bb, const float* __restrict__ alog,
                 const float* __restrict__ cw, const float* __restrict__ cb,
                 float* __restrict__ cP, float* __restrict__ cHe) {
  const int bc = blockIdx.x;            // b*NC + c
  const int b = bc >> 7, c = bc & (NC - 1);
  const int d = threadIdx.x;
  const int l0 = c * CH;
  const int base = b * L_ + l0;
  float a[16];
#pragma unroll
  for (int s4 = 0; s4 < 4; ++s4) {
    float4 v = *(const float4*)&alog[d * 16 + s4 * 4];
    a[s4*4+0] = -__expf(v.x); a[s4*4+1] = -__expf(v.y);
    a[s4*4+2] = -__expf(v.z); a[s4*4+3] = -__expf(v.w);
  }
  const float w0 = cw[d*4], w1 = cw[d*4+1], w2 = cw[d*4+2], w3 = cw[d*4+3];
  const float bias = cb[d];
  float x0 = (l0 >= 3) ? xz[(base - 3) * 512 + d] : 0.f;
  float x1 = (l0 >= 2) ? xz[(base - 2) * 512 + d] : 0.f;
  float x2 = (l0 >= 1) ? xz[(base - 1) * 512 + d] : 0.f;
  float h[16], P[16];
#pragma unroll
  for (int s = 0; s < 16; ++s) { h[s] = 0.f; P[s] = 1.f; }
  for (int l = 0; l < CH; ++l) {
    const int m = base + l;
    float x3  = xz[m * 512 + d];
    float dtv = dtf[m * 256 + d];
    const float4* Bp = (const float4*)&Bb[m * 16];
    float Bv[16];
    *(float4*)&Bv[0] = Bp[0]; *(float4*)&Bv[4]  = Bp[1];
    *(float4*)&Bv[8] = Bp[2]; *(float4*)&Bv[12] = Bp[3];
    float u = silu_f(fmaf(w0, x0, fmaf(w1, x1, fmaf(w2, x2, fmaf(w3, x3, bias)))));
    float du = dtv * u;
#pragma unroll
    for (int s = 0; s < 16; ++s) {
      float dA = __expf(dtv * a[s]);
      P[s] *= dA;
      h[s] = fmaf(dA, h[s], du * Bv[s]);
    }
    x0 = x1; x1 = x2; x2 = x3;
  }
#pragma unroll
  for (int s = 0; s < 16; ++s) {
    cP[(bc * 16 + s) * 256 + d]  = P[s];
    cHe[(bc * 16 + s) * 256 + d] = h[s];
  }
}

// ---------------------------------------------------------------------------
// Scan phase 2: serial stitch over chunks; h_start overwrites cP in place.
// ---------------------------------------------------------------------------
__global__ __launch_bounds__(256)
void scan_combine(float* __restrict__ cP, const float* __restrict__ cHe) {
  int tid = blockIdx.x * 256 + threadIdx.x;   // < 8*4096
  int b = tid >> 12;
  int sd = tid & 4095;                        // s*256 + d
  float hs = 0.f;
  for (int c = 0; c < NC; ++c) {
    int idx = (b * NC + c) * 4096 + sd;
    float p = cP[idx];
    float he = cHe[idx];
    cP[idx] = hs;                              // h_start for this chunk
    hs = fmaf(p, hs, he);
  }
}

// ---------------------------------------------------------------------------
// Scan phase 3: replay chunk from true h_start, y = h.C in registers,
// + u*D_skip, * silu(z); writes gated y over the z half of xz.
// ---------------------------------------------------------------------------
__global__ __launch_bounds__(256, 4)
void scan_phase3(const float* __restrict__ dtf,
                 const float* __restrict__ Bb, const float* __restrict__ Cb,
                 const float* __restrict__ alog,
                 const float* __restrict__ cw, const float* __restrict__ cb,
                 const float* __restrict__ hst, const float* __restrict__ dsk,
                 float* __restrict__ xz) {
  const int bc = blockIdx.x;
  const int b = bc >> 7, c = bc & (NC - 1);
  const int d = threadIdx.x;
  const int l0 = c * CH;
  const int base = b * L_ + l0;
  float a[16];
#pragma unroll
  for (int s4 = 0; s4 < 4; ++s4) {
    float4 v = *(const float4*)&alog[d * 16 + s4 * 4];
    a[s4*4+0] = -__expf(v.x); a[s4*4+1] = -__expf(v.y);
    a[s4*4+2] = -__expf(v.z); a[s4*4+3] = -__expf(v.w);
  }
  const float w0 = cw[d*4], w1 = cw[d*4+1], w2 = cw[d*4+2], w3 = cw[d*4+3];
  const float bias = cb[d];
  const float dskv = dsk[d];
  float x0 = (l0 >= 3) ? xz[(base - 3) * 512 + d] : 0.f;
  float x1 = (l0 >= 2) ? xz[(base - 2) * 512 + d] : 0.f;
  float x2 = (l0 >= 1) ? xz[(base - 1) * 512 + d] : 0.f;
  float h[16];
#pragma unroll
  for (int s = 0; s < 16; ++s) h[s] = hst[(bc * 16 + s) * 256 + d];
  for (int l = 0; l < CH; ++l) {
    const int m = base + l;
    float x3  = xz[m * 512 + d];
    float dtv = dtf[m * 256 + d];
    float zv  = xz[m * 512 + 256 + d];
    const float4* Bp = (const float4*)&Bb[m * 16];
    const float4* Cp = (const float4*)&Cb[m * 16];
    float Bv[16], Cv[16];
    *(float4*)&Bv[0] = Bp[0]; *(float4*)&Bv[4]  = Bp[1];
    *(float4*)&Bv[8] = Bp[2]; *(float4*)&Bv[12] = Bp[3];
    *(float4*)&Cv[0] = Cp[0]; *(float4*)&Cv[4]  = Cp[1];
    *(float4*)&Cv[8] = Cp[2]; *(float4*)&Cv[12] = Cp[3];
    float u = silu_f(fmaf(w0, x0, fmaf(w1, x1, fmaf(w2, x2, fmaf(w3, x3, bias)))));
    float du = dtv * u;
    float y = 0.f;
#pragma unroll
    for (int s = 0; s < 16; ++s) {
      float dA = __expf(dtv * a[s]);
      h[s] = fmaf(dA, h[s], du * Bv[s]);
      y = fmaf(h[s], Cv[s], y);
    }
    xz[m * 512 + 256 + d] = (y + u * dskv) * silu_f(zv);
    x0 = x1; x1 = x2; x2 = x3;
  }
}

// ---------------------------------------------------------------------------
// LayerNorm(128) + fc(128x128) + ReLU. 128 threads, 16 positions/block.
// ---------------------------------------------------------------------------
__global__ __launch_bounds__(128)
void ln_fc_relu(const float* __restrict__ Hin, const float* __restrict__ gamma,
                const float* __restrict__ beta, const float* __restrict__ fcw,
                float* __restrict__ out) {
  __shared__ float hn[DM];
  __shared__ float cwred[4];
  const int t = threadIdx.x;
  float wreg[DM];
#pragma unroll
  for (int k = 0; k < DM; ++k) wreg[k] = fcw[t * DM + k];
  const float g = gamma[t], be = beta[t];
  const int m0 = blockIdx.x * 16;
  for (int p = 0; p < 16; ++p) {
    const int m = m0 + p;
    float v = Hin[m * DM + t];
    float s1 = v, s2 = v * v;
#pragma unroll
    for (int msk = 1; msk < 64; msk <<= 1) {
      s1 += __shfl_xor(s1, msk);
      s2 += __shfl_xor(s2, msk);
    }
    if ((t & 63) == 0) { cwred[(t >> 6) * 2] = s1; cwred[(t >> 6) * 2 + 1] = s2; }
    __syncthreads();
    float S1 = cwred[0] + cwred[2], S2 = cwred[1] + cwred[3];
    float mu = S1 * (1.f / DM);
    float var = S2 * (1.f / DM) - mu * mu;
    float rs = rsqrtf(var + 1e-5f);
    hn[t] = (v - mu) * rs * g + be;
    __syncthreads();
    float acc = 0.f;
#pragma unroll
    for (int k = 0; k < DM; ++k) acc = fmaf(hn[k], wreg[k], acc);
    out[m * DM + t] = fmaxf(acc, 0.f);
    __syncthreads();
  }
}

extern "C" void kernel_launch(void* const* d_in, const int* in_sizes, int n_in,
                              void* d_out, int out_size, void* d_ws, size_t ws_size,
                              hipStream_t stream) {
  (void)in_sizes; (void)n_in; (void)out_size; (void)ws_size;
  const float* s    = (const float*)d_in[0];
  const float* w_in = (const float*)d_in[1];
  const float* cw   = (const float*)d_in[2];
  const float* cb   = (const float*)d_in[3];
  const float* xw   = (const float*)d_in[4];
  const float* dtw  = (const float*)d_in[5];
  const float* dtb  = (const float*)d_in[6];
  const float* alog = (const float*)d_in[7];
  const float* dsk  = (const float*)d_in[8];
  const float* ow   = (const float*)d_in[9];
  const float* gam  = (const float*)d_in[10];
  const float* bet  = (const float*)d_in[11];
  const float* fcw  = (const float*)d_in[12];
  float* out = (float*)d_out;
  float* ws  = (float*)d_ws;

  float* xz   = ws;                      // M*512  (x | z; z half later holds gated y)
  float* dtf  = ws + 16777216;           // M*256
  float* Bb   = ws + 25165824;           // M*16
  float* Cb   = ws + 25690112;           // M*16
  float* cP   = ws + 26214400;           // B*NC*4096  (later: h_start, then hmid)
  float* cHe  = ws + 30408704;           // B*NC*4096
  float* hmid = cP;                      // M*128, aliases cP (dead after phase 3)

  // 1. in_proj: xz = s @ W_in^T   (M x 512)
  gemm_nt<<<dim3(8, 512), 256, 0, stream>>>(s, 128, w_in, xz, 512, 128);
  // 2. fused conv/silu + x_proj + dt_proj
  xproj_dtproj<<<512, 256, 0, stream>>>(xz, xw, dtw, dtb, cw, cb, Bb, Cb, dtf);
  // 3-5. chunked selective scan (register-state formulation)
  scan_phase1<<<B_ * NC, 256, 0, stream>>>(xz, dtf, Bb, alog, cw, cb, cP, cHe);
  scan_combine<<<128, 256, 0, stream>>>(cP, cHe);
  scan_phase3<<<B_ * NC, 256, 0, stream>>>(dtf, Bb, Cb, alog, cw, cb, cP, dsk, xz);
  // 6. out_proj: hmid = y_gated @ out_proj_w^T
  gemm_nt<<<dim3(2, 512), 256, 0, stream>>>(xz + 256, 512, ow, hmid, 128, 256);
  // 7. LayerNorm + fc + ReLU
  ln_fc_relu<<<2048, 128, 0, stream>>>(hmid, gam, bet, fcw, out);
}

// Round 4
// 392.066 us; speedup vs baseline: 1.2938x; 1.0702x over previous
//
#include <hip/hip_runtime.h>
#include <math.h>

#define B_ 8
#define L_ 4096
#define DM 128
#define DI 256
#define DSN 16
#define RK 8
#define M_ (B_*L_)      // 32768 positions
#define NC 128          // number of scan chunks
#define CH 32           // chunk length (NC*CH == L_)

typedef __attribute__((ext_vector_type(8))) short bfrag;   // 8 bf16 (4 VGPRs)
typedef __attribute__((ext_vector_type(4))) float ffrag;   // 4 fp32 acc

__device__ __forceinline__ float silu_f(float x) { return x / (1.f + __expf(-x)); }

__device__ __forceinline__ unsigned short f2bf(float f) {
  unsigned int u = __builtin_bit_cast(unsigned int, f);
  unsigned int r = (u + 0x7FFFu + ((u >> 16) & 1u)) >> 16;   // RNE
  return (unsigned short)r;
}

// ---------------------------------------------------------------------------
// C[m,n] = sum_k A[m*lda + k] * W[n*K + k]   (A: M x K strided, W: N x K row-major)
// 64x64 tile, BK=16, 256 threads, 4x4 micro-tile per thread, float4 LDS reads.
// ---------------------------------------------------------------------------
__global__ __launch_bounds__(256)
void gemm_nt(const float* __restrict__ A, int lda,
             const float* __restrict__ W,
             float* __restrict__ C, int ldc,
             int K) {
  __shared__ float As[16][68];
  __shared__ float Ws[16][68];
  const int t  = threadIdx.x;
  const int tx = t & 15, ty = t >> 4;
  const int m0 = blockIdx.y << 6, n0 = blockIdx.x << 6;
  const int lr = t >> 2, lk = (t & 3) << 2;
  float acc[4][4] = {};
  const float* Ap = A + (m0 + lr) * lda + lk;
  const float* Wp = W + (n0 + lr) * K + lk;
  for (int k0 = 0; k0 < K; k0 += 16) {
    float4 av = *(const float4*)(Ap + k0);
    float4 wv = *(const float4*)(Wp + k0);
    __syncthreads();
    As[lk+0][lr] = av.x; As[lk+1][lr] = av.y; As[lk+2][lr] = av.z; As[lk+3][lr] = av.w;
    Ws[lk+0][lr] = wv.x; Ws[lk+1][lr] = wv.y; Ws[lk+2][lr] = wv.z; Ws[lk+3][lr] = wv.w;
    __syncthreads();
#pragma unroll
    for (int k = 0; k < 16; ++k) {
      float4 a4 = *(const float4*)&As[k][ty << 2];
      float4 w4 = *(const float4*)&Ws[k][tx << 2];
      float ar[4] = {a4.x, a4.y, a4.z, a4.w};
      float wr[4] = {w4.x, w4.y, w4.z, w4.w};
#pragma unroll
      for (int r = 0; r < 4; ++r)
#pragma unroll
        for (int c = 0; c < 4; ++c)
          acc[r][c] = fmaf(ar[r], wr[c], acc[r][c]);
    }
  }
#pragma unroll
  for (int r = 0; r < 4; ++r) {
    float4 o4 = make_float4(acc[r][0], acc[r][1], acc[r][2], acc[r][3]);
    *(float4*)&C[(m0 + (ty << 2) + r) * ldc + n0 + (tx << 2)] = o4;
  }
}

// ---------------------------------------------------------------------------
// Fused conv(4)+SiLU -> bf16 LDS -> MFMA x_proj -> dt_proj + softplus.
// 64 positions/block, 4 waves; wave w owns m-tile rows 16w..16w+15 and runs
// 3 n-tiles (48 cols, 40 real) x 8 K-step mfma_f32_16x16x32_bf16.
// No SMEM loads in hot loops (avoids OOO-SMEM lgkmcnt(0) drains vs DS).
// Outputs: Bb (M x 16), Cb (M x 16), dtf (M x 256) f32.
// ---------------------------------------------------------------------------
__global__ __launch_bounds__(256)
void xproj_dtproj(const float* __restrict__ xz, const float* __restrict__ xw,
                  const float* __restrict__ dtw, const float* __restrict__ dtb,
                  const float* __restrict__ cw, const float* __restrict__ cb,
                  float* __restrict__ Bb, float* __restrict__ Cb,
                  float* __restrict__ dtf) {
  __shared__ unsigned short ua[64 * 264];   // u bf16, row stride 264 (16B-aligned rows)
  __shared__ unsigned short wb[48 * 264];   // xw bf16 [n][k]; rows 40..47 garbage (discarded)
  __shared__ float dtr_s[64 * 12];          // x_proj outputs 0..7 per position
  const int t = threadIdx.x;
  const int p0 = blockIdx.x << 6;
  // stage u = bf16(silu(conv(x))): iter = position, lanes = channels (coalesced)
  for (int it = 0; it < 64; ++it) {
    int k = t;
    int m = p0 + it, l = m & (L_ - 1);
    float acc = cb[k];
#pragma unroll
    for (int j = 0; j < 4; ++j) {
      int ls = l - 3 + j;
      float v = (ls >= 0) ? xz[(m - 3 + j) * 512 + k] : 0.f;
      acc = fmaf(cw[k * 4 + j], v, acc);
    }
    ua[it * 264 + k] = f2bf(silu_f(acc));
  }
  // stage weights bf16
  for (int i = t; i < 40 * 256; i += 256) {
    int n = i >> 8, k = i & 255;
    wb[n * 264 + k] = f2bf(xw[i]);
  }
  __syncthreads();
  // MFMA phase
  const int w = t >> 6, l = t & 63;
  const int mrow = (w << 4) + (l & 15);     // A row (position within block)
  const int quad = l >> 4;
  ffrag acc0 = {0.f, 0.f, 0.f, 0.f}, acc1 = acc0, acc2 = acc0;
#pragma unroll
  for (int s = 0; s < 8; ++s) {
    int k0 = s * 32 + quad * 8;
    bfrag af = *(const bfrag*)&ua[mrow * 264 + k0];
    bfrag b0 = *(const bfrag*)&wb[(0  + (l & 15)) * 264 + k0];
    bfrag b1 = *(const bfrag*)&wb[(16 + (l & 15)) * 264 + k0];
    bfrag b2 = *(const bfrag*)&wb[(32 + (l & 15)) * 264 + k0];
    acc0 = __builtin_amdgcn_mfma_f32_16x16x32_bf16(af, b0, acc0, 0, 0, 0);
    acc1 = __builtin_amdgcn_mfma_f32_16x16x32_bf16(af, b1, acc1, 0, 0, 0);
    acc2 = __builtin_amdgcn_mfma_f32_16x16x32_bf16(af, b2, acc2, 0, 0, 0);
  }
  // scatter C: col = lane&15 (+n0), row = quad*4 + i
  const int col = l & 15;
#pragma unroll
  for (int i = 0; i < 4; ++i) {
    int ml = (w << 4) + quad * 4 + i;      // local position
    int m = p0 + ml;
    // n-tile 0: o = col (0..15)
    if (col < 8) dtr_s[ml * 12 + col] = acc0[i];
    else         Bb[m * 16 + (col - 8)] = acc0[i];
    // n-tile 1: o = 16+col (16..31)
    if (col < 8) Bb[m * 16 + 8 + col] = acc1[i];
    else         Cb[m * 16 + (col - 8)] = acc1[i];
    // n-tile 2: o = 32+col (32..47); only o<40 real
    if (col < 8) Cb[m * 16 + 8 + col] = acc2[i];
  }
  __syncthreads();
  // dt_proj + softplus: thread = channel d, dtr broadcast via DS (in-order)
  {
    const int d = t;
    float w8[8];
    *(float4*)&w8[0] = *(const float4*)&dtw[d * 8];
    *(float4*)&w8[4] = *(const float4*)&dtw[d * 8 + 4];
    const float bias = dtb[d];
    for (int pp = 0; pp < 64; ++pp) {
      float r0[8];
      *(float4*)&r0[0] = *(const float4*)&dtr_s[pp * 12];
      *(float4*)&r0[4] = *(const float4*)&dtr_s[pp * 12 + 4];
      float a2 = bias;
#pragma unroll
      for (int r2 = 0; r2 < 8; ++r2) a2 = fmaf(r0[r2], w8[r2], a2);
      float sp = (a2 > 20.f) ? a2 : log1pf(__expf(a2));
      dtf[(p0 + pp) * 256 + d] = sp;
    }
  }
}

// ---------------------------------------------------------------------------
// Scan phase 1: thread = channel d, all 16 states in registers. One block per
// (b, chunk). u recomputed via register-shift conv.
// Outputs cP/cHe layout [(b*NC+c), s, d].
// ---------------------------------------------------------------------------
__global__ __launch_bounds__(256, 4)
void scan_phase1(const float* __restrict__ xz, const float* __restrict__ dtf,
                 const float* __restrict__ Bb, const float* __restrict__ alog,
                 const float* __restrict__ cw, const float* __restrict__ cb,
                 float* __restrict__ cP, float* __restrict__ cHe) {
  const int bc = blockIdx.x;            // b*NC + c
  const int b = bc >> 7, c = bc & (NC - 1);
  const int d = threadIdx.x;
  const int l0 = c * CH;
  const int base = b * L_ + l0;
  float a[16];
#pragma unroll
  for (int s4 = 0; s4 < 4; ++s4) {
    float4 v = *(const float4*)&alog[d * 16 + s4 * 4];
    a[s4*4+0] = -__expf(v.x); a[s4*4+1] = -__expf(v.y);
    a[s4*4+2] = -__expf(v.z); a[s4*4+3] = -__expf(v.w);
  }
  const float w0 = cw[d*4], w1 = cw[d*4+1], w2 = cw[d*4+2], w3 = cw[d*4+3];
  const float bias = cb[d];
  float x0 = (l0 >= 3) ? xz[(base - 3) * 512 + d] : 0.f;
  float x1 = (l0 >= 2) ? xz[(base - 2) * 512 + d] : 0.f;
  float x2 = (l0 >= 1) ? xz[(base - 1) * 512 + d] : 0.f;
  float h[16], P[16];
#pragma unroll
  for (int s = 0; s < 16; ++s) { h[s] = 0.f; P[s] = 1.f; }
  for (int l = 0; l < CH; ++l) {
    const int m = base + l;
    float x3  = xz[m * 512 + d];
    float dtv = dtf[m * 256 + d];
    const float4* Bp = (const float4*)&Bb[m * 16];
    float Bv[16];
    *(float4*)&Bv[0] = Bp[0]; *(float4*)&Bv[4]  = Bp[1];
    *(float4*)&Bv[8] = Bp[2]; *(float4*)&Bv[12] = Bp[3];
    float u = silu_f(fmaf(w0, x0, fmaf(w1, x1, fmaf(w2, x2, fmaf(w3, x3, bias)))));
    float du = dtv * u;
#pragma unroll
    for (int s = 0; s < 16; ++s) {
      float dA = __expf(dtv * a[s]);
      P[s] *= dA;
      h[s] = fmaf(dA, h[s], du * Bv[s]);
    }
    x0 = x1; x1 = x2; x2 = x3;
  }
#pragma unroll
  for (int s = 0; s < 16; ++s) {
    cP[(bc * 16 + s) * 256 + d]  = P[s];
    cHe[(bc * 16 + s) * 256 + d] = h[s];
  }
}

// ---------------------------------------------------------------------------
// Scan phase 2: serial stitch over chunks; h_start overwrites cP in place.
// ---------------------------------------------------------------------------
__global__ __launch_bounds__(256)
void scan_combine(float* __restrict__ cP, const float* __restrict__ cHe) {
  int tid = blockIdx.x * 256 + threadIdx.x;   // < 8*4096
  int b = tid >> 12;
  int sd = tid & 4095;                        // s*256 + d
  float hs = 0.f;
  for (int c = 0; c < NC; ++c) {
    int idx = (b * NC + c) * 4096 + sd;
    float p = cP[idx];
    float he = cHe[idx];
    cP[idx] = hs;                              // h_start for this chunk
    hs = fmaf(p, hs, he);
  }
}

// ---------------------------------------------------------------------------
// Scan phase 3: replay chunk from true h_start, y = h.C in registers,
// + u*D_skip, * silu(z); writes gated y over the z half of xz.
// ---------------------------------------------------------------------------
__global__ __launch_bounds__(256, 4)
void scan_phase3(const float* __restrict__ dtf,
                 const float* __restrict__ Bb, const float* __restrict__ Cb,
                 const float* __restrict__ alog,
                 const float* __restrict__ cw, const float* __restrict__ cb,
                 const float* __restrict__ hst, const float* __restrict__ dsk,
                 float* __restrict__ xz) {
  const int bc = blockIdx.x;
  const int b = bc >> 7, c = bc & (NC - 1);
  const int d = threadIdx.x;
  const int l0 = c * CH;
  const int base = b * L_ + l0;
  float a[16];
#pragma unroll
  for (int s4 = 0; s4 < 4; ++s4) {
    float4 v = *(const float4*)&alog[d * 16 + s4 * 4];
    a[s4*4+0] = -__expf(v.x); a[s4*4+1] = -__expf(v.y);
    a[s4*4+2] = -__expf(v.z); a[s4*4+3] = -__expf(v.w);
  }
  const float w0 = cw[d*4], w1 = cw[d*4+1], w2 = cw[d*4+2], w3 = cw[d*4+3];
  const float bias = cb[d];
  const float dskv = dsk[d];
  float x0 = (l0 >= 3) ? xz[(base - 3) * 512 + d] : 0.f;
  float x1 = (l0 >= 2) ? xz[(base - 2) * 512 + d] : 0.f;
  float x2 = (l0 >= 1) ? xz[(base - 1) * 512 + d] : 0.f;
  float h[16];
#pragma unroll
  for (int s = 0; s < 16; ++s) h[s] = hst[(bc * 16 + s) * 256 + d];
  for (int l = 0; l < CH; ++l) {
    const int m = base + l;
    float x3  = xz[m * 512 + d];
    float dtv = dtf[m * 256 + d];
    float zv  = xz[m * 512 + 256 + d];
    const float4* Bp = (const float4*)&Bb[m * 16];
    const float4* Cp = (const float4*)&Cb[m * 16];
    float Bv[16], Cv[16];
    *(float4*)&Bv[0] = Bp[0]; *(float4*)&Bv[4]  = Bp[1];
    *(float4*)&Bv[8] = Bp[2]; *(float4*)&Bv[12] = Bp[3];
    *(float4*)&Cv[0] = Cp[0]; *(float4*)&Cv[4]  = Cp[1];
    *(float4*)&Cv[8] = Cp[2]; *(float4*)&Cv[12] = Cp[3];
    float u = silu_f(fmaf(w0, x0, fmaf(w1, x1, fmaf(w2, x2, fmaf(w3, x3, bias)))));
    float du = dtv * u;
    float y = 0.f;
#pragma unroll
    for (int s = 0; s < 16; ++s) {
      float dA = __expf(dtv * a[s]);
      h[s] = fmaf(dA, h[s], du * Bv[s]);
      y = fmaf(h[s], Cv[s], y);
    }
    xz[m * 512 + 256 + d] = (y + u * dskv) * silu_f(zv);
    x0 = x1; x1 = x2; x2 = x3;
  }
}

// ---------------------------------------------------------------------------
// LayerNorm(128) + fc(128x128) + ReLU. 128 threads, 16 positions/block.
// ---------------------------------------------------------------------------
__global__ __launch_bounds__(128)
void ln_fc_relu(const float* __restrict__ Hin, const float* __restrict__ gamma,
                const float* __restrict__ beta, const float* __restrict__ fcw,
                float* __restrict__ out) {
  __shared__ float hn[DM];
  __shared__ float cwred[4];
  const int t = threadIdx.x;
  float wreg[DM];
#pragma unroll
  for (int k = 0; k < DM; ++k) wreg[k] = fcw[t * DM + k];
  const float g = gamma[t], be = beta[t];
  const int m0 = blockIdx.x * 16;
  for (int p = 0; p < 16; ++p) {
    const int m = m0 + p;
    float v = Hin[m * DM + t];
    float s1 = v, s2 = v * v;
#pragma unroll
    for (int msk = 1; msk < 64; msk <<= 1) {
      s1 += __shfl_xor(s1, msk);
      s2 += __shfl_xor(s2, msk);
    }
    if ((t & 63) == 0) { cwred[(t >> 6) * 2] = s1; cwred[(t >> 6) * 2 + 1] = s2; }
    __syncthreads();
    float S1 = cwred[0] + cwred[2], S2 = cwred[1] + cwred[3];
    float mu = S1 * (1.f / DM);
    float var = S2 * (1.f / DM) - mu * mu;
    float rs = rsqrtf(var + 1e-5f);
    hn[t] = (v - mu) * rs * g + be;
    __syncthreads();
    float acc = 0.f;
#pragma unroll
    for (int k = 0; k < DM; ++k) acc = fmaf(hn[k], wreg[k], acc);
    out[m * DM + t] = fmaxf(acc, 0.f);
    __syncthreads();
  }
}

extern "C" void kernel_launch(void* const* d_in, const int* in_sizes, int n_in,
                              void* d_out, int out_size, void* d_ws, size_t ws_size,
                              hipStream_t stream) {
  (void)in_sizes; (void)n_in; (void)out_size; (void)ws_size;
  const float* s    = (const float*)d_in[0];
  const float* w_in = (const float*)d_in[1];
  const float* cw   = (const float*)d_in[2];
  const float* cb   = (const float*)d_in[3];
  const float* xw   = (const float*)d_in[4];
  const float* dtw  = (const float*)d_in[5];
  const float* dtb  = (const float*)d_in[6];
  const float* alog = (const float*)d_in[7];
  const float* dsk  = (const float*)d_in[8];
  const float* ow   = (const float*)d_in[9];
  const float* gam  = (const float*)d_in[10];
  const float* bet  = (const float*)d_in[11];
  const float* fcw  = (const float*)d_in[12];
  float* out = (float*)d_out;
  float* ws  = (float*)d_ws;

  float* xz   = ws;                      // M*512  (x | z; z half later holds gated y)
  float* dtf  = ws + 16777216;           // M*256
  float* Bb   = ws + 25165824;           // M*16
  float* Cb   = ws + 25690112;           // M*16
  float* cP   = ws + 26214400;           // B*NC*4096  (later: h_start, then hmid)
  float* cHe  = ws + 30408704;           // B*NC*4096
  float* hmid = cP;                      // M*128, aliases cP (dead after phase 3)

  // 1. in_proj: xz = s @ W_in^T   (M x 512)
  gemm_nt<<<dim3(8, 512), 256, 0, stream>>>(s, 128, w_in, xz, 512, 128);
  // 2. fused conv/silu + x_proj (MFMA) + dt_proj
  xproj_dtproj<<<512, 256, 0, stream>>>(xz, xw, dtw, dtb, cw, cb, Bb, Cb, dtf);
  // 3-5. chunked selective scan (register-state formulation)
  scan_phase1<<<B_ * NC, 256, 0, stream>>>(xz, dtf, Bb, alog, cw, cb, cP, cHe);
  scan_combine<<<128, 256, 0, stream>>>(cP, cHe);
  scan_phase3<<<B_ * NC, 256, 0, stream>>>(dtf, Bb, Cb, alog, cw, cb, cP, dsk, xz);
  // 6. out_proj: hmid = y_gated @ out_proj_w^T
  gemm_nt<<<dim3(2, 512), 256, 0, stream>>>(xz + 256, 512, ow, hmid, 128, 256);
  // 7. LayerNorm + fc + ReLU
  ln_fc_relu<<<2048, 128, 0, stream>>>(hmid, gam, bet, fcw, out);
}

// Round 5
// 343.928 us; speedup vs baseline: 1.4748x; 1.1400x over previous
//
#include <hip/hip_runtime.h>
#include <math.h>

#define B_ 8
#define L_ 4096
#define DM 128
#define DI 256
#define DSN 16
#define RK 8
#define M_ (B_*L_)      // 32768 positions
#define NC 128          // number of scan chunks
#define CH 32           // chunk length (NC*CH == L_)

typedef __attribute__((ext_vector_type(8))) short bfrag;   // 8 bf16 (4 VGPRs)
typedef __attribute__((ext_vector_type(4))) float ffrag;   // 4 fp32 acc

__device__ __forceinline__ float silu_f(float x) { return x / (1.f + __expf(-x)); }

__device__ __forceinline__ unsigned short f2bf(float f) {
  unsigned int u = __builtin_bit_cast(unsigned int, f);
  unsigned int r = (u + 0x7FFFu + ((u >> 16) & 1u)) >> 16;   // RNE
  return (unsigned short)r;
}
__device__ __forceinline__ unsigned int f2bf2(float lo, float hi) {
  return (unsigned int)f2bf(lo) | ((unsigned int)f2bf(hi) << 16);
}

// ---------------------------------------------------------------------------
// f32 SIMT GEMM (kept for out_proj): C[m,n] = sum_k A[m*lda+k] * W[n*K+k]
// ---------------------------------------------------------------------------
__global__ __launch_bounds__(256)
void gemm_nt(const float* __restrict__ A, int lda,
             const float* __restrict__ W,
             float* __restrict__ C, int ldc,
             int K) {
  __shared__ float As[16][68];
  __shared__ float Ws[16][68];
  const int t  = threadIdx.x;
  const int tx = t & 15, ty = t >> 4;
  const int m0 = blockIdx.y << 6, n0 = blockIdx.x << 6;
  const int lr = t >> 2, lk = (t & 3) << 2;
  float acc[4][4] = {};
  const float* Ap = A + (m0 + lr) * lda + lk;
  const float* Wp = W + (n0 + lr) * K + lk;
  for (int k0 = 0; k0 < K; k0 += 16) {
    float4 av = *(const float4*)(Ap + k0);
    float4 wv = *(const float4*)(Wp + k0);
    __syncthreads();
    As[lk+0][lr] = av.x; As[lk+1][lr] = av.y; As[lk+2][lr] = av.z; As[lk+3][lr] = av.w;
    Ws[lk+0][lr] = wv.x; Ws[lk+1][lr] = wv.y; Ws[lk+2][lr] = wv.z; Ws[lk+3][lr] = wv.w;
    __syncthreads();
#pragma unroll
    for (int k = 0; k < 16; ++k) {
      float4 a4 = *(const float4*)&As[k][ty << 2];
      float4 w4 = *(const float4*)&Ws[k][tx << 2];
      float ar[4] = {a4.x, a4.y, a4.z, a4.w};
      float wr[4] = {w4.x, w4.y, w4.z, w4.w};
#pragma unroll
      for (int r = 0; r < 4; ++r)
#pragma unroll
        for (int c = 0; c < 4; ++c)
          acc[r][c] = fmaf(ar[r], wr[c], acc[r][c]);
    }
  }
#pragma unroll
  for (int r = 0; r < 4; ++r) {
    float4 o4 = make_float4(acc[r][0], acc[r][1], acc[r][2], acc[r][3]);
    *(float4*)&C[(m0 + (ty << 2) + r) * ldc + n0 + (tx << 2)] = o4;
  }
}

// ---------------------------------------------------------------------------
// in_proj bf16 MFMA GEMM: C[m,n] = sum_k A[m*128+k] * W[n*128+k], K=128 in one
// LDS staging (f32 -> bf16 convert in-flight). 64x64 tile, 256 threads,
// 4 waves x 4 n-subtiles x 4 K-steps of mfma_f32_16x16x32_bf16.
// ---------------------------------------------------------------------------
__global__ __launch_bounds__(256)
void gemm_bf16_in(const float* __restrict__ A, const float* __restrict__ W,
                  float* __restrict__ C) {
  __shared__ unsigned short As[64 * 136];   // [m][k], row stride 272 B (16B mult)
  __shared__ unsigned short Ws[64 * 136];   // [n][k]
  const int t = threadIdx.x;
  const int m0 = blockIdx.y << 6, n0 = blockIdx.x << 6;
  // stage + convert: 64 rows x 32 float4 each
  for (int i = t; i < 64 * 32; i += 256) {
    int row = i >> 5, c4 = i & 31;
    float4 av = *(const float4*)&A[(m0 + row) * 128 + (c4 << 2)];
    float4 wv = *(const float4*)&W[(n0 + row) * 128 + (c4 << 2)];
    uint2 ap = {f2bf2(av.x, av.y), f2bf2(av.z, av.w)};
    uint2 wp = {f2bf2(wv.x, wv.y), f2bf2(wv.z, wv.w)};
    *(uint2*)&As[row * 136 + (c4 << 2)] = ap;
    *(uint2*)&Ws[row * 136 + (c4 << 2)] = wp;
  }
  __syncthreads();
  const int w = t >> 6, l = t & 63, q = l >> 4, col = l & 15;
  ffrag acc[4] = {{0.f,0.f,0.f,0.f},{0.f,0.f,0.f,0.f},{0.f,0.f,0.f,0.f},{0.f,0.f,0.f,0.f}};
#pragma unroll
  for (int s = 0; s < 4; ++s) {
    int k0 = s * 32 + q * 8;
    bfrag af = *(const bfrag*)&As[((w << 4) + col) * 136 + k0];
#pragma unroll
    for (int nt = 0; nt < 4; ++nt) {
      bfrag bf_ = *(const bfrag*)&Ws[((nt << 4) + col) * 136 + k0];
      acc[nt] = __builtin_amdgcn_mfma_f32_16x16x32_bf16(af, bf_, acc[nt], 0, 0, 0);
    }
  }
#pragma unroll
  for (int nt = 0; nt < 4; ++nt)
#pragma unroll
    for (int i = 0; i < 4; ++i) {
      int ml = (w << 4) + (q << 2) + i;
      C[(m0 + ml) * 512 + n0 + (nt << 4) + col] = acc[nt][i];
    }
}

// ---------------------------------------------------------------------------
// Fused conv(4)+SiLU -> bf16 LDS -> MFMA x_proj -> dt_proj + softplus.
// 512 threads. Staging: thread = (half, channel), rolling-window conv
// (1 load/iter, 32 serial iters). MFMA: 12 tiles over 8 waves.
// Outputs: Bb (M x 16), Cb (M x 16), dtf (M x 256) f32.
// ---------------------------------------------------------------------------
__global__ __launch_bounds__(512)
void xproj_dtproj(const float* __restrict__ xz, const float* __restrict__ xw,
                  const float* __restrict__ dtw, const float* __restrict__ dtb,
                  const float* __restrict__ cw, const float* __restrict__ cb,
                  float* __restrict__ Bb, float* __restrict__ Cb,
                  float* __restrict__ dtf) {
  __shared__ unsigned short ua[64 * 264];   // u bf16, row stride 528 B
  __shared__ unsigned short wb[48 * 264];   // xw bf16 [n][k]; rows 40..47 garbage
  __shared__ float dtr_s[64 * 12];          // x_proj outputs 0..7 per position
  const int t = threadIdx.x;
  const int p0 = blockIdx.x << 6;
  // stage u = bf16(silu(conv(x))): rolling window, halves of 32 positions
  {
    const int k = t & 255, half = t >> 8;
    const int pstart = half << 5;
    const int base = p0 + pstart;
    const int lb = base & (L_ - 1);          // block is 64-aligned in sequence
    const float w0 = cw[k*4], w1 = cw[k*4+1], w2 = cw[k*4+2], w3 = cw[k*4+3];
    const float bias = cb[k];
    float x0 = (lb >= 3) ? xz[(base - 3) * 512 + k] : 0.f;
    float x1 = (lb >= 2) ? xz[(base - 2) * 512 + k] : 0.f;
    float x2 = (lb >= 1) ? xz[(base - 1) * 512 + k] : 0.f;
#pragma unroll 8
    for (int it = 0; it < 32; ++it) {
      float x3 = xz[(base + it) * 512 + k];
      float u = silu_f(fmaf(w0, x0, fmaf(w1, x1, fmaf(w2, x2, fmaf(w3, x3, bias)))));
      ua[(pstart + it) * 264 + k] = f2bf(u);
      x0 = x1; x1 = x2; x2 = x3;
    }
  }
  // stage weights bf16
  for (int i = t; i < 40 * 256; i += 512) {
    int n = i >> 8, k = i & 255;
    wb[n * 264 + k] = f2bf(xw[i]);
  }
  __syncthreads();
  // MFMA phase: 12 tiles (4 m x 3 n) over 8 waves
  const int w = t >> 6, l = t & 63, q = l >> 4, col = l & 15;
  for (int tile = w; tile < 12; tile += 8) {
    const int mt = tile & 3, nt = tile >> 2;
    ffrag acc = {0.f, 0.f, 0.f, 0.f};
#pragma unroll
    for (int s = 0; s < 8; ++s) {
      int k0 = s * 32 + q * 8;
      bfrag af = *(const bfrag*)&ua[((mt << 4) + col) * 264 + k0];
      bfrag bf_ = *(const bfrag*)&wb[((nt << 4) + col) * 264 + k0];
      acc = __builtin_amdgcn_mfma_f32_16x16x32_bf16(af, bf_, acc, 0, 0, 0);
    }
#pragma unroll
    for (int i = 0; i < 4; ++i) {
      int ml = (mt << 4) + (q << 2) + i;
      int m = p0 + ml;
      if (nt == 0) {
        if (col < 8) dtr_s[ml * 12 + col] = acc[i];
        else         Bb[m * 16 + (col - 8)] = acc[i];
      } else if (nt == 1) {
        if (col < 8) Bb[m * 16 + 8 + col] = acc[i];
        else         Cb[m * 16 + (col - 8)] = acc[i];
      } else {
        if (col < 8) Cb[m * 16 + 8 + col] = acc[i];
      }
    }
  }
  __syncthreads();
  // dt_proj + softplus: thread = (half, channel), dtr broadcast via DS
  {
    const int d = t & 255, half = t >> 8;
    const int pstart = half << 5;
    float w8[8];
    *(float4*)&w8[0] = *(const float4*)&dtw[d * 8];
    *(float4*)&w8[4] = *(const float4*)&dtw[d * 8 + 4];
    const float bias = dtb[d];
#pragma unroll 4
    for (int pp = pstart; pp < pstart + 32; ++pp) {
      float r0[8];
      *(float4*)&r0[0] = *(const float4*)&dtr_s[pp * 12];
      *(float4*)&r0[4] = *(const float4*)&dtr_s[pp * 12 + 4];
      float a2 = bias;
#pragma unroll
      for (int r2 = 0; r2 < 8; ++r2) a2 = fmaf(r0[r2], w8[r2], a2);
      float sp = (a2 > 20.f) ? a2 : log1pf(__expf(a2));
      dtf[(p0 + pp) * 256 + d] = sp;
    }
  }
}

// ---------------------------------------------------------------------------
// Scan phase 1: thread = channel d, all 16 states in registers.
// ---------------------------------------------------------------------------
__global__ __launch_bounds__(256, 4)
void scan_phase1(const float* __restrict__ xz, const float* __restrict__ dtf,
                 const float* __restrict__ Bb, const float* __restrict__ alog,
                 const float* __restrict__ cw, const float* __restrict__ cb,
                 float* __restrict__ cP, float* __restrict__ cHe) {
  const int bc = blockIdx.x;            // b*NC + c
  const int b = bc >> 7, c = bc & (NC - 1);
  const int d = threadIdx.x;
  const int l0 = c * CH;
  const int base = b * L_ + l0;
  float a[16];
#pragma unroll
  for (int s4 = 0; s4 < 4; ++s4) {
    float4 v = *(const float4*)&alog[d * 16 + s4 * 4];
    a[s4*4+0] = -__expf(v.x); a[s4*4+1] = -__expf(v.y);
    a[s4*4+2] = -__expf(v.z); a[s4*4+3] = -__expf(v.w);
  }
  const float w0 = cw[d*4], w1 = cw[d*4+1], w2 = cw[d*4+2], w3 = cw[d*4+3];
  const float bias = cb[d];
  float x0 = (l0 >= 3) ? xz[(base - 3) * 512 + d] : 0.f;
  float x1 = (l0 >= 2) ? xz[(base - 2) * 512 + d] : 0.f;
  float x2 = (l0 >= 1) ? xz[(base - 1) * 512 + d] : 0.f;
  float h[16], P[16];
#pragma unroll
  for (int s = 0; s < 16; ++s) { h[s] = 0.f; P[s] = 1.f; }
  for (int l = 0; l < CH; ++l) {
    const int m = base + l;
    float x3  = xz[m * 512 + d];
    float dtv = dtf[m * 256 + d];
    const float4* Bp = (const float4*)&Bb[m * 16];
    float Bv[16];
    *(float4*)&Bv[0] = Bp[0]; *(float4*)&Bv[4]  = Bp[1];
    *(float4*)&Bv[8] = Bp[2]; *(float4*)&Bv[12] = Bp[3];
    float u = silu_f(fmaf(w0, x0, fmaf(w1, x1, fmaf(w2, x2, fmaf(w3, x3, bias)))));
    float du = dtv * u;
#pragma unroll
    for (int s = 0; s < 16; ++s) {
      float dA = __expf(dtv * a[s]);
      P[s] *= dA;
      h[s] = fmaf(dA, h[s], du * Bv[s]);
    }
    x0 = x1; x1 = x2; x2 = x3;
  }
#pragma unroll
  for (int s = 0; s < 16; ++s) {
    cP[(bc * 16 + s) * 256 + d]  = P[s];
    cHe[(bc * 16 + s) * 256 + d] = h[s];
  }
}

// ---------------------------------------------------------------------------
// Scan phase 2: serial stitch over chunks; h_start overwrites cP in place.
// ---------------------------------------------------------------------------
__global__ __launch_bounds__(256)
void scan_combine(float* __restrict__ cP, const float* __restrict__ cHe) {
  int tid = blockIdx.x * 256 + threadIdx.x;   // < 8*4096
  int b = tid >> 12;
  int sd = tid & 4095;                        // s*256 + d
  float hs = 0.f;
  for (int c = 0; c < NC; ++c) {
    int idx = (b * NC + c) * 4096 + sd;
    float p = cP[idx];
    float he = cHe[idx];
    cP[idx] = hs;                              // h_start for this chunk
    hs = fmaf(p, hs, he);
  }
}

// ---------------------------------------------------------------------------
// Scan phase 3: replay chunk from true h_start, y = h.C in registers,
// + u*D_skip, * silu(z); writes gated y over the z half of xz.
// ---------------------------------------------------------------------------
__global__ __launch_bounds__(256, 4)
void scan_phase3(const float* __restrict__ dtf,
                 const float* __restrict__ Bb, const float* __restrict__ Cb,
                 const float* __restrict__ alog,
                 const float* __restrict__ cw, const float* __restrict__ cb,
                 const float* __restrict__ hst, const float* __restrict__ dsk,
                 float* __restrict__ xz) {
  const int bc = blockIdx.x;
  const int b = bc >> 7, c = bc & (NC - 1);
  const int d = threadIdx.x;
  const int l0 = c * CH;
  const int base = b * L_ + l0;
  float a[16];
#pragma unroll
  for (int s4 = 0; s4 < 4; ++s4) {
    float4 v = *(const float4*)&alog[d * 16 + s4 * 4];
    a[s4*4+0] = -__expf(v.x); a[s4*4+1] = -__expf(v.y);
    a[s4*4+2] = -__expf(v.z); a[s4*4+3] = -__expf(v.w);
  }
  const float w0 = cw[d*4], w1 = cw[d*4+1], w2 = cw[d*4+2], w3 = cw[d*4+3];
  const float bias = cb[d];
  const float dskv = dsk[d];
  float x0 = (l0 >= 3) ? xz[(base - 3) * 512 + d] : 0.f;
  float x1 = (l0 >= 2) ? xz[(base - 2) * 512 + d] : 0.f;
  float x2 = (l0 >= 1) ? xz[(base - 1) * 512 + d] : 0.f;
  float h[16];
#pragma unroll
  for (int s = 0; s < 16; ++s) h[s] = hst[(bc * 16 + s) * 256 + d];
  for (int l = 0; l < CH; ++l) {
    const int m = base + l;
    float x3  = xz[m * 512 + d];
    float dtv = dtf[m * 256 + d];
    float zv  = xz[m * 512 + 256 + d];
    const float4* Bp = (const float4*)&Bb[m * 16];
    const float4* Cp = (const float4*)&Cb[m * 16];
    float Bv[16], Cv[16];
    *(float4*)&Bv[0] = Bp[0]; *(float4*)&Bv[4]  = Bp[1];
    *(float4*)&Bv[8] = Bp[2]; *(float4*)&Bv[12] = Bp[3];
    *(float4*)&Cv[0] = Cp[0]; *(float4*)&Cv[4]  = Cp[1];
    *(float4*)&Cv[8] = Cp[2]; *(float4*)&Cv[12] = Cp[3];
    float u = silu_f(fmaf(w0, x0, fmaf(w1, x1, fmaf(w2, x2, fmaf(w3, x3, bias)))));
    float du = dtv * u;
    float y = 0.f;
#pragma unroll
    for (int s = 0; s < 16; ++s) {
      float dA = __expf(dtv * a[s]);
      h[s] = fmaf(dA, h[s], du * Bv[s]);
      y = fmaf(h[s], Cv[s], y);
    }
    xz[m * 512 + 256 + d] = (y + u * dskv) * silu_f(zv);
    x0 = x1; x1 = x2; x2 = x3;
  }
}

// ---------------------------------------------------------------------------
// LayerNorm(128) + fc(128x128) + ReLU. 128 threads, 16 positions/block.
// ---------------------------------------------------------------------------
__global__ __launch_bounds__(128)
void ln_fc_relu(const float* __restrict__ Hin, const float* __restrict__ gamma,
                const float* __restrict__ beta, const float* __restrict__ fcw,
                float* __restrict__ out) {
  __shared__ float hn[DM];
  __shared__ float cwred[4];
  const int t = threadIdx.x;
  float wreg[DM];
#pragma unroll
  for (int k = 0; k < DM; ++k) wreg[k] = fcw[t * DM + k];
  const float g = gamma[t], be = beta[t];
  const int m0 = blockIdx.x * 16;
  for (int p = 0; p < 16; ++p) {
    const int m = m0 + p;
    float v = Hin[m * DM + t];
    float s1 = v, s2 = v * v;
#pragma unroll
    for (int msk = 1; msk < 64; msk <<= 1) {
      s1 += __shfl_xor(s1, msk);
      s2 += __shfl_xor(s2, msk);
    }
    if ((t & 63) == 0) { cwred[(t >> 6) * 2] = s1; cwred[(t >> 6) * 2 + 1] = s2; }
    __syncthreads();
    float S1 = cwred[0] + cwred[2], S2 = cwred[1] + cwred[3];
    float mu = S1 * (1.f / DM);
    float var = S2 * (1.f / DM) - mu * mu;
    float rs = rsqrtf(var + 1e-5f);
    hn[t] = (v - mu) * rs * g + be;
    __syncthreads();
    float acc = 0.f;
#pragma unroll
    for (int k = 0; k < DM; ++k) acc = fmaf(hn[k], wreg[k], acc);
    out[m * DM + t] = fmaxf(acc, 0.f);
    __syncthreads();
  }
}

extern "C" void kernel_launch(void* const* d_in, const int* in_sizes, int n_in,
                              void* d_out, int out_size, void* d_ws, size_t ws_size,
                              hipStream_t stream) {
  (void)in_sizes; (void)n_in; (void)out_size; (void)ws_size;
  const float* s    = (const float*)d_in[0];
  const float* w_in = (const float*)d_in[1];
  const float* cw   = (const float*)d_in[2];
  const float* cb   = (const float*)d_in[3];
  const float* xw   = (const float*)d_in[4];
  const float* dtw  = (const float*)d_in[5];
  const float* dtb  = (const float*)d_in[6];
  const float* alog = (const float*)d_in[7];
  const float* dsk  = (const float*)d_in[8];
  const float* ow   = (const float*)d_in[9];
  const float* gam  = (const float*)d_in[10];
  const float* bet  = (const float*)d_in[11];
  const float* fcw  = (const float*)d_in[12];
  float* out = (float*)d_out;
  float* ws  = (float*)d_ws;

  float* xz   = ws;                      // M*512  (x | z; z half later holds gated y)
  float* dtf  = ws + 16777216;           // M*256
  float* Bb   = ws + 25165824;           // M*16
  float* Cb   = ws + 25690112;           // M*16
  float* cP   = ws + 26214400;           // B*NC*4096  (later: h_start, then hmid)
  float* cHe  = ws + 30408704;           // B*NC*4096
  float* hmid = cP;                      // M*128, aliases cP (dead after phase 3)

  // 1. in_proj: xz = s @ W_in^T   (M x 512), bf16 MFMA
  gemm_bf16_in<<<dim3(8, 512), 256, 0, stream>>>(s, w_in, xz);
  // 2. fused conv/silu + x_proj (MFMA) + dt_proj
  xproj_dtproj<<<512, 512, 0, stream>>>(xz, xw, dtw, dtb, cw, cb, Bb, Cb, dtf);
  // 3-5. chunked selective scan (register-state formulation)
  scan_phase1<<<B_ * NC, 256, 0, stream>>>(xz, dtf, Bb, alog, cw, cb, cP, cHe);
  scan_combine<<<128, 256, 0, stream>>>(cP, cHe);
  scan_phase3<<<B_ * NC, 256, 0, stream>>>(dtf, Bb, Cb, alog, cw, cb, cP, dsk, xz);
  // 6. out_proj: hmid = y_gated @ out_proj_w^T
  gemm_nt<<<dim3(2, 512), 256, 0, stream>>>(xz + 256, 512, ow, hmid, 128, 256);
  // 7. LayerNorm + fc + ReLU
  ln_fc_relu<<<2048, 128, 0, stream>>>(hmid, gam, bet, fcw, out);
}

// Round 7
// 285.550 us; speedup vs baseline: 1.7764x; 1.2044x over previous
//
#include <hip/hip_runtime.h>
#include <math.h>

#define B_ 8
#define L_ 4096
#define DM 128
#define DI 256
#define DSN 16
#define RK 8
#define M_ (B_*L_)      // 32768 positions
#define NC 128          // number of scan chunks
#define CH 32           // chunk length (NC*CH == L_)

typedef __attribute__((ext_vector_type(8))) short bfrag;   // 8 bf16 (4 VGPRs)
typedef __attribute__((ext_vector_type(4))) float ffrag;   // 4 fp32 acc

__device__ __forceinline__ float silu_f(float x) { return x / (1.f + __expf(-x)); }

__device__ __forceinline__ unsigned short f2bf(float f) {
  unsigned int u = __builtin_bit_cast(unsigned int, f);
  unsigned int r = (u + 0x7FFFu + ((u >> 16) & 1u)) >> 16;   // RNE
  return (unsigned short)r;
}
__device__ __forceinline__ unsigned int f2bf2(float lo, float hi) {
  return (unsigned int)f2bf(lo) | ((unsigned int)f2bf(hi) << 16);
}

// ---------------------------------------------------------------------------
// in_proj bf16 MFMA GEMM: C[m,n] = sum_k A[m*128+k] * W[n*128+k], K=128.
// 64x64 tile, 256 threads, 4 waves x 4 n-subtiles x 4 K-steps.
// ---------------------------------------------------------------------------
__global__ __launch_bounds__(256)
void gemm_bf16_in(const float* __restrict__ A, const float* __restrict__ W,
                  float* __restrict__ C) {
  __shared__ unsigned short As[64 * 136];   // [m][k], row stride 272 B
  __shared__ unsigned short Ws[64 * 136];   // [n][k]
  const int t = threadIdx.x;
  const int m0 = blockIdx.y << 6, n0 = blockIdx.x << 6;
  for (int i = t; i < 64 * 32; i += 256) {
    int row = i >> 5, c4 = i & 31;
    float4 av = *(const float4*)&A[(m0 + row) * 128 + (c4 << 2)];
    float4 wv = *(const float4*)&W[(n0 + row) * 128 + (c4 << 2)];
    uint2 ap = {f2bf2(av.x, av.y), f2bf2(av.z, av.w)};
    uint2 wp = {f2bf2(wv.x, wv.y), f2bf2(wv.z, wv.w)};
    *(uint2*)&As[row * 136 + (c4 << 2)] = ap;
    *(uint2*)&Ws[row * 136 + (c4 << 2)] = wp;
  }
  __syncthreads();
  const int w = t >> 6, l = t & 63, q = l >> 4, col = l & 15;
  ffrag acc[4] = {{0.f,0.f,0.f,0.f},{0.f,0.f,0.f,0.f},{0.f,0.f,0.f,0.f},{0.f,0.f,0.f,0.f}};
#pragma unroll
  for (int s = 0; s < 4; ++s) {
    int k0 = s * 32 + q * 8;
    bfrag af = *(const bfrag*)&As[((w << 4) + col) * 136 + k0];
#pragma unroll
    for (int nt = 0; nt < 4; ++nt) {
      bfrag bf_ = *(const bfrag*)&Ws[((nt << 4) + col) * 136 + k0];
      acc[nt] = __builtin_amdgcn_mfma_f32_16x16x32_bf16(af, bf_, acc[nt], 0, 0, 0);
    }
  }
#pragma unroll
  for (int nt = 0; nt < 4; ++nt)
#pragma unroll
    for (int i = 0; i < 4; ++i) {
      int ml = (w << 4) + (q << 2) + i;
      C[(m0 + ml) * 512 + n0 + (nt << 4) + col] = acc[nt][i];
    }
}

// ---------------------------------------------------------------------------
// out_proj bf16 MFMA GEMM: C[m,n] = sum_k A[m*512+k] * W[n*256+k], K=256.
// A = gated-y half of xz (stride 512). 64x64 tile, 4 waves x 4 n x 8 K-steps.
// ---------------------------------------------------------------------------
__global__ __launch_bounds__(256)
void gemm_bf16_out(const float* __restrict__ A, const float* __restrict__ W,
                   float* __restrict__ C) {
  __shared__ unsigned short As[64 * 264];   // [m][k], row stride 528 B
  __shared__ unsigned short Ws[64 * 264];   // [n][k]
  const int t = threadIdx.x;
  const int m0 = blockIdx.y << 6, n0 = blockIdx.x << 6;
  for (int i = t; i < 64 * 64; i += 256) {
    int row = i >> 6, c4 = i & 63;
    float4 av = *(const float4*)&A[(m0 + row) * 512 + (c4 << 2)];
    float4 wv = *(const float4*)&W[(n0 + row) * 256 + (c4 << 2)];
    uint2 ap = {f2bf2(av.x, av.y), f2bf2(av.z, av.w)};
    uint2 wp = {f2bf2(wv.x, wv.y), f2bf2(wv.z, wv.w)};
    *(uint2*)&As[row * 264 + (c4 << 2)] = ap;
    *(uint2*)&Ws[row * 264 + (c4 << 2)] = wp;
  }
  __syncthreads();
  const int w = t >> 6, l = t & 63, q = l >> 4, col = l & 15;
  ffrag acc[4] = {{0.f,0.f,0.f,0.f},{0.f,0.f,0.f,0.f},{0.f,0.f,0.f,0.f},{0.f,0.f,0.f,0.f}};
#pragma unroll
  for (int s = 0; s < 8; ++s) {
    int k0 = s * 32 + q * 8;
    bfrag af = *(const bfrag*)&As[((w << 4) + col) * 264 + k0];
#pragma unroll
    for (int nt = 0; nt < 4; ++nt) {
      bfrag bf_ = *(const bfrag*)&Ws[((nt << 4) + col) * 264 + k0];
      acc[nt] = __builtin_amdgcn_mfma_f32_16x16x32_bf16(af, bf_, acc[nt], 0, 0, 0);
    }
  }
#pragma unroll
  for (int nt = 0; nt < 4; ++nt)
#pragma unroll
    for (int i = 0; i < 4; ++i) {
      int ml = (w << 4) + (q << 2) + i;
      C[(m0 + ml) * 128 + n0 + (nt << 4) + col] = acc[nt][i];
    }
}

// ---------------------------------------------------------------------------
// Fused conv(4)+SiLU -> bf16 LDS -> MFMA x_proj -> dt_proj + softplus.
// wb rows 40..47 are zero-filled: no MFMA input ever reads uninitialized LDS.
// ---------------------------------------------------------------------------
__global__ __launch_bounds__(512)
void xproj_dtproj(const float* __restrict__ xz, const float* __restrict__ xw,
                  const float* __restrict__ dtw, const float* __restrict__ dtb,
                  const float* __restrict__ cw, const float* __restrict__ cb,
                  float* __restrict__ Bb, float* __restrict__ Cb,
                  float* __restrict__ dtf) {
  __shared__ unsigned short ua[64 * 264];   // u bf16
  __shared__ unsigned short wb[48 * 264];   // xw bf16 [n][k]; rows 40..47 zeroed
  __shared__ float dtr_s[64 * 12];          // x_proj outputs 0..7 per position
  const int t = threadIdx.x;
  const int p0 = blockIdx.x << 6;
  {
    const int k = t & 255, half = t >> 8;
    const int pstart = half << 5;
    const int base = p0 + pstart;
    const int lb = base & (L_ - 1);          // block is 64-aligned in sequence
    const float w0 = cw[k*4], w1 = cw[k*4+1], w2 = cw[k*4+2], w3 = cw[k*4+3];
    const float bias = cb[k];
    float x0 = (lb >= 3) ? xz[(base - 3) * 512 + k] : 0.f;
    float x1 = (lb >= 2) ? xz[(base - 2) * 512 + k] : 0.f;
    float x2 = (lb >= 1) ? xz[(base - 1) * 512 + k] : 0.f;
#pragma unroll 8
    for (int it = 0; it < 32; ++it) {
      float x3 = xz[(base + it) * 512 + k];
      float u = silu_f(fmaf(w0, x0, fmaf(w1, x1, fmaf(w2, x2, fmaf(w3, x3, bias)))));
      ua[(pstart + it) * 264 + k] = f2bf(u);
      x0 = x1; x1 = x2; x2 = x3;
    }
  }
  for (int i = t; i < 40 * 256; i += 512) {
    int n = i >> 8, k = i & 255;
    wb[n * 264 + k] = f2bf(xw[i]);
  }
  for (int i = t; i < 8 * 264; i += 512) wb[40 * 264 + i] = 0;   // zero pad rows
  __syncthreads();
  const int w = t >> 6, l = t & 63, q = l >> 4, col = l & 15;
  for (int tile = w; tile < 12; tile += 8) {
    const int mt = tile & 3, nt = tile >> 2;
    ffrag acc = {0.f, 0.f, 0.f, 0.f};
#pragma unroll
    for (int s = 0; s < 8; ++s) {
      int k0 = s * 32 + q * 8;
      bfrag af = *(const bfrag*)&ua[((mt << 4) + col) * 264 + k0];
      bfrag bf_ = *(const bfrag*)&wb[((nt << 4) + col) * 264 + k0];
      acc = __builtin_amdgcn_mfma_f32_16x16x32_bf16(af, bf_, acc, 0, 0, 0);
    }
#pragma unroll
    for (int i = 0; i < 4; ++i) {
      int ml = (mt << 4) + (q << 2) + i;
      int m = p0 + ml;
      if (nt == 0) {
        if (col < 8) dtr_s[ml * 12 + col] = acc[i];
        else         Bb[m * 16 + (col - 8)] = acc[i];
      } else if (nt == 1) {
        if (col < 8) Bb[m * 16 + 8 + col] = acc[i];
        else         Cb[m * 16 + (col - 8)] = acc[i];
      } else {
        if (col < 8) Cb[m * 16 + 8 + col] = acc[i];
      }
    }
  }
  __syncthreads();
  {
    const int d = t & 255, half = t >> 8;
    const int pstart = half << 5;
    float w8[8];
    *(float4*)&w8[0] = *(const float4*)&dtw[d * 8];
    *(float4*)&w8[4] = *(const float4*)&dtw[d * 8 + 4];
    const float bias = dtb[d];
#pragma unroll 4
    for (int pp = pstart; pp < pstart + 32; ++pp) {
      float r0[8];
      *(float4*)&r0[0] = *(const float4*)&dtr_s[pp * 12];
      *(float4*)&r0[4] = *(const float4*)&dtr_s[pp * 12 + 4];
      float a2 = bias;
#pragma unroll
      for (int r2 = 0; r2 < 8; ++r2) a2 = fmaf(r0[r2], w8[r2], a2);
      float sp = (a2 > 20.f) ? a2 : log1pf(__expf(a2));
      dtf[(p0 + pp) * 256 + d] = sp;
    }
  }
}

// ---------------------------------------------------------------------------
// Scan phase 1: thread = channel d, all 16 states in registers.
// ---------------------------------------------------------------------------
__global__ __launch_bounds__(256, 4)
void scan_phase1(const float* __restrict__ xz, const float* __restrict__ dtf,
                 const float* __restrict__ Bb, const float* __restrict__ alog,
                 const float* __restrict__ cw, const float* __restrict__ cb,
                 float* __restrict__ cP, float* __restrict__ cHe) {
  const int bc = blockIdx.x;            // b*NC + c
  const int b = bc >> 7, c = bc & (NC - 1);
  const int d = threadIdx.x;
  const int l0 = c * CH;
  const int base = b * L_ + l0;
  float a[16];
#pragma unroll
  for (int s4 = 0; s4 < 4; ++s4) {
    float4 v = *(const float4*)&alog[d * 16 + s4 * 4];
    a[s4*4+0] = -__expf(v.x); a[s4*4+1] = -__expf(v.y);
    a[s4*4+2] = -__expf(v.z); a[s4*4+3] = -__expf(v.w);
  }
  const float w0 = cw[d*4], w1 = cw[d*4+1], w2 = cw[d*4+2], w3 = cw[d*4+3];
  const float bias = cb[d];
  float x0 = (l0 >= 3) ? xz[(base - 3) * 512 + d] : 0.f;
  float x1 = (l0 >= 2) ? xz[(base - 2) * 512 + d] : 0.f;
  float x2 = (l0 >= 1) ? xz[(base - 1) * 512 + d] : 0.f;
  float h[16], P[16];
#pragma unroll
  for (int s = 0; s < 16; ++s) { h[s] = 0.f; P[s] = 1.f; }
  for (int l = 0; l < CH; ++l) {
    const int m = base + l;
    float x3  = xz[m * 512 + d];
    float dtv = dtf[m * 256 + d];
    const float4* Bp = (const float4*)&Bb[m * 16];
    float Bv[16];
    *(float4*)&Bv[0] = Bp[0]; *(float4*)&Bv[4]  = Bp[1];
    *(float4*)&Bv[8] = Bp[2]; *(float4*)&Bv[12] = Bp[3];
    float u = silu_f(fmaf(w0, x0, fmaf(w1, x1, fmaf(w2, x2, fmaf(w3, x3, bias)))));
    float du = dtv * u;
#pragma unroll
    for (int s = 0; s < 16; ++s) {
      float dA = __expf(dtv * a[s]);
      P[s] *= dA;
      h[s] = fmaf(dA, h[s], du * Bv[s]);
    }
    x0 = x1; x1 = x2; x2 = x3;
  }
#pragma unroll
  for (int s = 0; s < 16; ++s) {
    cP[(bc * 16 + s) * 256 + d]  = P[s];
    cHe[(bc * 16 + s) * 256 + d] = h[s];
  }
}

// ---------------------------------------------------------------------------
// Scan phase 2: serial stitch over chunks; h_start overwrites cP in place.
// ---------------------------------------------------------------------------
__global__ __launch_bounds__(256)
void scan_combine(float* __restrict__ cP, const float* __restrict__ cHe) {
  int tid = blockIdx.x * 256 + threadIdx.x;   // < 8*4096
  int b = tid >> 12;
  int sd = tid & 4095;                        // s*256 + d
  float hs = 0.f;
  for (int c = 0; c < NC; ++c) {
    int idx = (b * NC + c) * 4096 + sd;
    float p = cP[idx];
    float he = cHe[idx];
    cP[idx] = hs;                              // h_start for this chunk
    hs = fmaf(p, hs, he);
  }
}

// ---------------------------------------------------------------------------
// Scan phase 3: replay chunk from true h_start, y = h.C in registers,
// + u*D_skip, * silu(z); writes gated y over the z half of xz.
// ---------------------------------------------------------------------------
__global__ __launch_bounds__(256, 4)
void scan_phase3(const float* __restrict__ dtf,
                 const float* __restrict__ Bb, const float* __restrict__ Cb,
                 const float* __restrict__ alog,
                 const float* __restrict__ cw, const float* __restrict__ cb,
                 const float* __restrict__ hst, const float* __restrict__ dsk,
                 float* __restrict__ xz) {
  const int bc = blockIdx.x;
  const int b = bc >> 7, c = bc & (NC - 1);
  const int d = threadIdx.x;
  const int l0 = c * CH;
  const int base = b * L_ + l0;
  float a[16];
#pragma unroll
  for (int s4 = 0; s4 < 4; ++s4) {
    float4 v = *(const float4*)&alog[d * 16 + s4 * 4];
    a[s4*4+0] = -__expf(v.x); a[s4*4+1] = -__expf(v.y);
    a[s4*4+2] = -__expf(v.z); a[s4*4+3] = -__expf(v.w);
  }
  const float w0 = cw[d*4], w1 = cw[d*4+1], w2 = cw[d*4+2], w3 = cw[d*4+3];
  const float bias = cb[d];
  const float dskv = dsk[d];
  float x0 = (l0 >= 3) ? xz[(base - 3) * 512 + d] : 0.f;
  float x1 = (l0 >= 2) ? xz[(base - 2) * 512 + d] : 0.f;
  float x2 = (l0 >= 1) ? xz[(base - 1) * 512 + d] : 0.f;
  float h[16];
#pragma unroll
  for (int s = 0; s < 16; ++s) h[s] = hst[(bc * 16 + s) * 256 + d];
  for (int l = 0; l < CH; ++l) {
    const int m = base + l;
    float x3  = xz[m * 512 + d];
    float dtv = dtf[m * 256 + d];
    float zv  = xz[m * 512 + 256 + d];
    const float4* Bp = (const float4*)&Bb[m * 16];
    const float4* Cp = (const float4*)&Cb[m * 16];
    float Bv[16], Cv[16];
    *(float4*)&Bv[0] = Bp[0]; *(float4*)&Bv[4]  = Bp[1];
    *(float4*)&Bv[8] = Bp[2]; *(float4*)&Bv[12] = Bp[3];
    *(float4*)&Cv[0] = Cp[0]; *(float4*)&Cv[4]  = Cp[1];
    *(float4*)&Cv[8] = Cp[2]; *(float4*)&Cv[12] = Cp[3];
    float u = silu_f(fmaf(w0, x0, fmaf(w1, x1, fmaf(w2, x2, fmaf(w3, x3, bias)))));
    float du = dtv * u;
    float y = 0.f;
#pragma unroll
    for (int s = 0; s < 16; ++s) {
      float dA = __expf(dtv * a[s]);
      h[s] = fmaf(dA, h[s], du * Bv[s]);
      y = fmaf(h[s], Cv[s], y);
    }
    xz[m * 512 + 256 + d] = (y + u * dskv) * silu_f(zv);
    x0 = x1; x1 = x2; x2 = x3;
  }
}

// ---------------------------------------------------------------------------
// LayerNorm(128) + fc(128x128) + ReLU via MFMA. 64 positions/block, 256 thr.
// ---------------------------------------------------------------------------
__global__ __launch_bounds__(256)
void ln_fc_mfma(const float* __restrict__ Hin, const float* __restrict__ gamma,
                const float* __restrict__ beta, const float* __restrict__ fcw,
                float* __restrict__ out) {
  __shared__ unsigned short hnb[64 * 136];  // normalized bf16 [p][k]
  __shared__ unsigned short wb[128 * 136];  // fcw bf16 [n][k]
  const int t = threadIdx.x;
  const int p0 = blockIdx.x << 6;
  {
    const int r = t >> 2, qd = t & 3;
    const float* hp = &Hin[(p0 + r) * 128 + (qd << 5)];
    float v[32];
#pragma unroll
    for (int j = 0; j < 8; ++j) *(float4*)&v[j << 2] = *(const float4*)&hp[j << 2];
    float s1 = 0.f, s2 = 0.f;
#pragma unroll
    for (int j = 0; j < 32; ++j) { s1 += v[j]; s2 = fmaf(v[j], v[j], s2); }
    s1 += __shfl_xor(s1, 1); s2 += __shfl_xor(s2, 1);
    s1 += __shfl_xor(s1, 2); s2 += __shfl_xor(s2, 2);
    float mu = s1 * (1.f / DM);
    float var = s2 * (1.f / DM) - mu * mu;
    float rs = rsqrtf(var + 1e-5f);
    const float* gp = &gamma[qd << 5];
    const float* bp = &beta[qd << 5];
#pragma unroll
    for (int j = 0; j < 16; ++j) {
      float h0 = fmaf((v[2*j]   - mu) * rs, gp[2*j],   bp[2*j]);
      float h1 = fmaf((v[2*j+1] - mu) * rs, gp[2*j+1], bp[2*j+1]);
      *(unsigned int*)&hnb[r * 136 + (qd << 5) + 2*j] = f2bf2(h0, h1);
    }
  }
  for (int i = t; i < 128 * 32; i += 256) {
    int row = i >> 5, c4 = i & 31;
    float4 wv = *(const float4*)&fcw[row * 128 + (c4 << 2)];
    uint2 wp = {f2bf2(wv.x, wv.y), f2bf2(wv.z, wv.w)};
    *(uint2*)&wb[row * 136 + (c4 << 2)] = wp;
  }
  __syncthreads();
  const int w = t >> 6, l = t & 63, q = l >> 4, col = l & 15;
  ffrag acc[8] = {{0.f,0.f,0.f,0.f},{0.f,0.f,0.f,0.f},{0.f,0.f,0.f,0.f},{0.f,0.f,0.f,0.f},
                  {0.f,0.f,0.f,0.f},{0.f,0.f,0.f,0.f},{0.f,0.f,0.f,0.f},{0.f,0.f,0.f,0.f}};
#pragma unroll
  for (int s = 0; s < 4; ++s) {
    int k0 = s * 32 + q * 8;
    bfrag af = *(const bfrag*)&hnb[((w << 4) + col) * 136 + k0];
#pragma unroll
    for (int nt = 0; nt < 8; ++nt) {
      bfrag bf_ = *(const bfrag*)&wb[((nt << 4) + col) * 136 + k0];
      acc[nt] = __builtin_amdgcn_mfma_f32_16x16x32_bf16(af, bf_, acc[nt], 0, 0, 0);
    }
  }
#pragma unroll
  for (int nt = 0; nt < 8; ++nt)
#pragma unroll
    for (int i = 0; i < 4; ++i) {
      int ml = (w << 4) + (q << 2) + i;
      out[(p0 + ml) * 128 + (nt << 4) + col] = fmaxf(acc[nt][i], 0.f);
    }
}

extern "C" void kernel_launch(void* const* d_in, const int* in_sizes, int n_in,
                              void* d_out, int out_size, void* d_ws, size_t ws_size,
                              hipStream_t stream) {
  (void)in_sizes; (void)n_in; (void)out_size; (void)ws_size;
  const float* s    = (const float*)d_in[0];
  const float* w_in = (const float*)d_in[1];
  const float* cw   = (const float*)d_in[2];
  const float* cb   = (const float*)d_in[3];
  const float* xw   = (const float*)d_in[4];
  const float* dtw  = (const float*)d_in[5];
  const float* dtb  = (const float*)d_in[6];
  const float* alog = (const float*)d_in[7];
  const float* dsk  = (const float*)d_in[8];
  const float* ow   = (const float*)d_in[9];
  const float* gam  = (const float*)d_in[10];
  const float* bet  = (const float*)d_in[11];
  const float* fcw  = (const float*)d_in[12];
  float* out = (float*)d_out;
  float* ws  = (float*)d_ws;

  float* xz   = ws;                      // M*512  (x | z; z half later holds gated y)
  float* dtf  = ws + 16777216;           // M*256
  float* Bb   = ws + 25165824;           // M*16
  float* Cb   = ws + 25690112;           // M*16
  float* cP   = ws + 26214400;           // B*NC*4096  (later: h_start)
  float* cHe  = ws + 30408704;           // B*NC*4096
  float* hmid = ws + 34603008;           // M*128 — own region, no aliasing

  // 1. in_proj: xz = s @ W_in^T   (M x 512), bf16 MFMA
  gemm_bf16_in<<<dim3(8, 512), 256, 0, stream>>>(s, w_in, xz);
  // 2. fused conv/silu + x_proj (MFMA) + dt_proj
  xproj_dtproj<<<512, 512, 0, stream>>>(xz, xw, dtw, dtb, cw, cb, Bb, Cb, dtf);
  // 3-5. chunked selective scan (register-state formulation)
  scan_phase1<<<B_ * NC, 256, 0, stream>>>(xz, dtf, Bb, alog, cw, cb, cP, cHe);
  scan_combine<<<128, 256, 0, stream>>>(cP, cHe);
  scan_phase3<<<B_ * NC, 256, 0, stream>>>(dtf, Bb, Cb, alog, cw, cb, cP, dsk, xz);
  // 6. out_proj: hmid = y_gated @ out_proj_w^T, bf16 MFMA
  gemm_bf16_out<<<dim3(2, 512), 256, 0, stream>>>(xz + 256, ow, hmid);
  // 7. LayerNorm + fc + ReLU, bf16 MFMA
  ln_fc_mfma<<<512, 256, 0, stream>>>(hmid, gam, bet, fcw, out);
}

// Round 8
// 279.181 us; speedup vs baseline: 1.8169x; 1.0228x over previous
//
#include <hip/hip_runtime.h>
#include <math.h>

#define B_ 8
#define L_ 4096
#define DM 128
#define DI 256
#define DSN 16
#define RK 8
#define M_ (B_*L_)      // 32768 positions
#define NC 128          // number of scan chunks
#define CH 32           // chunk length (NC*CH == L_)

typedef __attribute__((ext_vector_type(8))) short bfrag;   // 8 bf16 (4 VGPRs)
typedef __attribute__((ext_vector_type(4))) float ffrag;   // 4 fp32 acc

__device__ __forceinline__ float silu_f(float x) { return x / (1.f + __expf(-x)); }

__device__ __forceinline__ unsigned short f2bf(float f) {
  unsigned int u = __builtin_bit_cast(unsigned int, f);
  unsigned int r = (u + 0x7FFFu + ((u >> 16) & 1u)) >> 16;   // RNE
  return (unsigned short)r;
}
__device__ __forceinline__ unsigned int f2bf2(float lo, float hi) {
  return (unsigned int)f2bf(lo) | ((unsigned int)f2bf(hi) << 16);
}
__device__ __forceinline__ float bf2f(unsigned short us) {
  return __builtin_bit_cast(float, ((unsigned int)us) << 16);
}

// ---------------------------------------------------------------------------
// in_proj bf16 MFMA GEMM. Outputs split: x-half -> xq (f32, M x 256),
// z-half -> zb (bf16, M x 256). K=128, 64x64 tile, 256 threads.
// ---------------------------------------------------------------------------
__global__ __launch_bounds__(256)
void gemm_bf16_in(const float* __restrict__ A, const float* __restrict__ W,
                  float* __restrict__ xq, unsigned short* __restrict__ zb) {
  __shared__ unsigned short As[64 * 136];   // [m][k]
  __shared__ unsigned short Ws[64 * 136];   // [n][k]
  const int t = threadIdx.x;
  const int m0 = blockIdx.y << 6, n0 = blockIdx.x << 6;
  for (int i = t; i < 64 * 32; i += 256) {
    int row = i >> 5, c4 = i & 31;
    float4 av = *(const float4*)&A[(m0 + row) * 128 + (c4 << 2)];
    float4 wv = *(const float4*)&W[(n0 + row) * 128 + (c4 << 2)];
    uint2 ap = {f2bf2(av.x, av.y), f2bf2(av.z, av.w)};
    uint2 wp = {f2bf2(wv.x, wv.y), f2bf2(wv.z, wv.w)};
    *(uint2*)&As[row * 136 + (c4 << 2)] = ap;
    *(uint2*)&Ws[row * 136 + (c4 << 2)] = wp;
  }
  __syncthreads();
  const int w = t >> 6, l = t & 63, q = l >> 4, col = l & 15;
  ffrag acc[4] = {{0.f,0.f,0.f,0.f},{0.f,0.f,0.f,0.f},{0.f,0.f,0.f,0.f},{0.f,0.f,0.f,0.f}};
#pragma unroll
  for (int s = 0; s < 4; ++s) {
    int k0 = s * 32 + q * 8;
    bfrag af = *(const bfrag*)&As[((w << 4) + col) * 136 + k0];
#pragma unroll
    for (int nt = 0; nt < 4; ++nt) {
      bfrag bf_ = *(const bfrag*)&Ws[((nt << 4) + col) * 136 + k0];
      acc[nt] = __builtin_amdgcn_mfma_f32_16x16x32_bf16(af, bf_, acc[nt], 0, 0, 0);
    }
  }
#pragma unroll
  for (int nt = 0; nt < 4; ++nt)
#pragma unroll
    for (int i = 0; i < 4; ++i) {
      int ml = (w << 4) + (q << 2) + i;
      int n = n0 + (nt << 4) + col;
      int m = m0 + ml;
      if (n < 256) xq[m * 256 + n] = acc[nt][i];
      else         zb[m * 256 + (n - 256)] = f2bf(acc[nt][i]);
    }
}

// ---------------------------------------------------------------------------
// out_proj bf16 MFMA GEMM: A = yb (bf16, M x 256), W f32 (128 x 256), K=256.
// ---------------------------------------------------------------------------
__global__ __launch_bounds__(256)
void gemm_bf16_out(const unsigned short* __restrict__ Ab, const float* __restrict__ W,
                   float* __restrict__ C) {
  __shared__ unsigned short As[64 * 264];
  __shared__ unsigned short Ws[64 * 264];
  const int t = threadIdx.x;
  const int m0 = blockIdx.y << 6, n0 = blockIdx.x << 6;
  for (int i = t; i < 64 * 32; i += 256) {       // A: 64 rows x 32 x (8 bf16)
    int row = i >> 5, c8 = i & 31;
    uint4 av = *(const uint4*)&Ab[(m0 + row) * 256 + (c8 << 3)];
    *(uint4*)&As[row * 264 + (c8 << 3)] = av;
  }
  for (int i = t; i < 64 * 64; i += 256) {       // W: convert f32 -> bf16
    int row = i >> 6, c4 = i & 63;
    float4 wv = *(const float4*)&W[(n0 + row) * 256 + (c4 << 2)];
    uint2 wp = {f2bf2(wv.x, wv.y), f2bf2(wv.z, wv.w)};
    *(uint2*)&Ws[row * 264 + (c4 << 2)] = wp;
  }
  __syncthreads();
  const int w = t >> 6, l = t & 63, q = l >> 4, col = l & 15;
  ffrag acc[4] = {{0.f,0.f,0.f,0.f},{0.f,0.f,0.f,0.f},{0.f,0.f,0.f,0.f},{0.f,0.f,0.f,0.f}};
#pragma unroll
  for (int s = 0; s < 8; ++s) {
    int k0 = s * 32 + q * 8;
    bfrag af = *(const bfrag*)&As[((w << 4) + col) * 264 + k0];
#pragma unroll
    for (int nt = 0; nt < 4; ++nt) {
      bfrag bf_ = *(const bfrag*)&Ws[((nt << 4) + col) * 264 + k0];
      acc[nt] = __builtin_amdgcn_mfma_f32_16x16x32_bf16(af, bf_, acc[nt], 0, 0, 0);
    }
  }
#pragma unroll
  for (int nt = 0; nt < 4; ++nt)
#pragma unroll
    for (int i = 0; i < 4; ++i) {
      int ml = (w << 4) + (q << 2) + i;
      C[(m0 + ml) * 128 + n0 + (nt << 4) + col] = acc[nt][i];
    }
}

// ---------------------------------------------------------------------------
// Fused conv(4)+SiLU -> bf16 LDS -> MFMA x_proj -> dt_proj + softplus.
// Also emits u (bf16) and dt (bf16) streams for the scan phases.
// ---------------------------------------------------------------------------
__global__ __launch_bounds__(512)
void xproj_dtproj(const float* __restrict__ xq, const float* __restrict__ xw,
                  const float* __restrict__ dtw, const float* __restrict__ dtpb,
                  const float* __restrict__ cw, const float* __restrict__ cb,
                  float* __restrict__ Bb, float* __restrict__ Cb,
                  unsigned short* __restrict__ ub, unsigned short* __restrict__ dtb16) {
  __shared__ unsigned short ua[64 * 264];   // u bf16
  __shared__ unsigned short wb[48 * 264];   // xw bf16; rows 40..47 zeroed
  __shared__ float dtr_s[64 * 12];
  const int t = threadIdx.x;
  const int p0 = blockIdx.x << 6;
  {
    const int k = t & 255, half = t >> 8;
    const int pstart = half << 5;
    const int base = p0 + pstart;
    const int lb = base & (L_ - 1);
    const float w0 = cw[k*4], w1 = cw[k*4+1], w2 = cw[k*4+2], w3 = cw[k*4+3];
    const float bias = cb[k];
    float x0 = (lb >= 3) ? xq[(base - 3) * 256 + k] : 0.f;
    float x1 = (lb >= 2) ? xq[(base - 2) * 256 + k] : 0.f;
    float x2 = (lb >= 1) ? xq[(base - 1) * 256 + k] : 0.f;
#pragma unroll 8
    for (int it = 0; it < 32; ++it) {
      float x3 = xq[(base + it) * 256 + k];
      float u = silu_f(fmaf(w0, x0, fmaf(w1, x1, fmaf(w2, x2, fmaf(w3, x3, bias)))));
      unsigned short ub16 = f2bf(u);
      ua[(pstart + it) * 264 + k] = ub16;
      ub[(base + it) * 256 + k] = ub16;
      x0 = x1; x1 = x2; x2 = x3;
    }
  }
  for (int i = t; i < 40 * 256; i += 512) {
    int n = i >> 8, k = i & 255;
    wb[n * 264 + k] = f2bf(xw[i]);
  }
  for (int i = t; i < 8 * 264; i += 512) wb[40 * 264 + i] = 0;
  __syncthreads();
  const int w = t >> 6, l = t & 63, q = l >> 4, col = l & 15;
  for (int tile = w; tile < 12; tile += 8) {
    const int mt = tile & 3, nt = tile >> 2;
    ffrag acc = {0.f, 0.f, 0.f, 0.f};
#pragma unroll
    for (int s = 0; s < 8; ++s) {
      int k0 = s * 32 + q * 8;
      bfrag af = *(const bfrag*)&ua[((mt << 4) + col) * 264 + k0];
      bfrag bf_ = *(const bfrag*)&wb[((nt << 4) + col) * 264 + k0];
      acc = __builtin_amdgcn_mfma_f32_16x16x32_bf16(af, bf_, acc, 0, 0, 0);
    }
#pragma unroll
    for (int i = 0; i < 4; ++i) {
      int ml = (mt << 4) + (q << 2) + i;
      int m = p0 + ml;
      if (nt == 0) {
        if (col < 8) dtr_s[ml * 12 + col] = acc[i];
        else         Bb[m * 16 + (col - 8)] = acc[i];
      } else if (nt == 1) {
        if (col < 8) Bb[m * 16 + 8 + col] = acc[i];
        else         Cb[m * 16 + (col - 8)] = acc[i];
      } else {
        if (col < 8) Cb[m * 16 + 8 + col] = acc[i];
      }
    }
  }
  __syncthreads();
  {
    const int d = t & 255, half = t >> 8;
    const int pstart = half << 5;
    float w8[8];
    *(float4*)&w8[0] = *(const float4*)&dtw[d * 8];
    *(float4*)&w8[4] = *(const float4*)&dtw[d * 8 + 4];
    const float bias = dtpb[d];
#pragma unroll 4
    for (int pp = pstart; pp < pstart + 32; ++pp) {
      float r0[8];
      *(float4*)&r0[0] = *(const float4*)&dtr_s[pp * 12];
      *(float4*)&r0[4] = *(const float4*)&dtr_s[pp * 12 + 4];
      float a2 = bias;
#pragma unroll
      for (int r2 = 0; r2 < 8; ++r2) a2 = fmaf(r0[r2], w8[r2], a2);
      float sp = (a2 > 20.f) ? a2 : log1pf(__expf(a2));
      dtb16[(p0 + pp) * 256 + d] = f2bf(sp);
    }
  }
}

// ---------------------------------------------------------------------------
// Scan phase 1: 512 threads; wave covers 32 channels x 2 state-halves
// (d = w*32 + (l&31), sh = l>>5, 8 states each). P via exp(a*sum(dt)).
// Fast path (wave-verified a[s] = -(s+1)): dA via powers of exp(-dt).
// ---------------------------------------------------------------------------
__global__ __launch_bounds__(512, 4)
void scan_phase1(const unsigned short* __restrict__ ub,
                 const unsigned short* __restrict__ dtb,
                 const float* __restrict__ Bb, const float* __restrict__ alog,
                 float* __restrict__ cP, float* __restrict__ cHe) {
  const int bc = blockIdx.x;
  const int b = bc >> 7, c = bc & (NC - 1);
  const int t = threadIdx.x;
  const int l = t & 63, w = t >> 6;
  const int d = (w << 5) + (l & 31);
  const int sh = l >> 5;
  const int soff = sh << 3;
  const int base = b * L_ + c * CH;
  float a[8];
  bool okl = true;
#pragma unroll
  for (int j = 0; j < 8; ++j) {
    a[j] = -__expf(alog[d * 16 + soff + j]);
    float tgt = (float)(soff + j + 1);
    okl = okl && (fabsf(a[j] + tgt) <= 1e-3f * tgt);
  }
  const bool fast = (bool)__all((int)okl);
  float h[8] = {};
  float sdt = 0.f;
  for (int ll = 0; ll < CH; ++ll) {
    const int m = base + ll;
    float dtv = bf2f(dtb[m * 256 + d]);
    float uv  = bf2f(ub[m * 256 + d]);
    float Bv[8];
    *(float4*)&Bv[0] = *(const float4*)&Bb[m * 16 + soff];
    *(float4*)&Bv[4] = *(const float4*)&Bb[m * 16 + soff + 4];
    float du = dtv * uv;
    sdt += dtv;
    if (fast) {
      float e1 = __expf(-dtv);
      float e2 = e1 * e1, e4 = e2 * e2, e8 = e4 * e4;
      float dA = sh ? e8 * e1 : e1;
#pragma unroll
      for (int j = 0; j < 8; ++j) {
        h[j] = fmaf(dA, h[j], du * Bv[j]);
        dA *= e1;
      }
    } else {
#pragma unroll
      for (int j = 0; j < 8; ++j) {
        float dA = __expf(dtv * a[j]);
        h[j] = fmaf(dA, h[j], du * Bv[j]);
      }
    }
  }
#pragma unroll
  for (int j = 0; j < 8; ++j) {
    int o = (bc * 16 + soff + j) * 256 + d;
    cP[o]  = __expf(a[j] * sdt);
    cHe[o] = h[j];
  }
}

// ---------------------------------------------------------------------------
// Scan phase 2: serial stitch over chunks; h_start overwrites cP in place.
// ---------------------------------------------------------------------------
__global__ __launch_bounds__(256)
void scan_combine(float* __restrict__ cP, const float* __restrict__ cHe) {
  int tid = blockIdx.x * 256 + threadIdx.x;   // < 8*4096
  int b = tid >> 12;
  int sd = tid & 4095;
  float hs = 0.f;
  for (int c = 0; c < NC; ++c) {
    int idx = (b * NC + c) * 4096 + sd;
    float p = cP[idx];
    float he = cHe[idx];
    cP[idx] = hs;
    hs = fmaf(p, hs, he);
  }
}

// ---------------------------------------------------------------------------
// Scan phase 3: replay from h_start; y = h.C, cross-half via shfl_xor(y,32);
// gated output written bf16 to yb.
// ---------------------------------------------------------------------------
__global__ __launch_bounds__(512, 4)
void scan_phase3(const unsigned short* __restrict__ ub,
                 const unsigned short* __restrict__ dtb,
                 const float* __restrict__ Bb, const float* __restrict__ Cb,
                 const float* __restrict__ alog, const float* __restrict__ hst,
                 const float* __restrict__ dsk,
                 const unsigned short* __restrict__ zb,
                 unsigned short* __restrict__ yb) {
  const int bc = blockIdx.x;
  const int b = bc >> 7, c = bc & (NC - 1);
  const int t = threadIdx.x;
  const int l = t & 63, w = t >> 6;
  const int d = (w << 5) + (l & 31);
  const int sh = l >> 5;
  const int soff = sh << 3;
  const int base = b * L_ + c * CH;
  float a[8];
  bool okl = true;
#pragma unroll
  for (int j = 0; j < 8; ++j) {
    a[j] = -__expf(alog[d * 16 + soff + j]);
    float tgt = (float)(soff + j + 1);
    okl = okl && (fabsf(a[j] + tgt) <= 1e-3f * tgt);
  }
  const bool fast = (bool)__all((int)okl);
  const float dskv = dsk[d];
  float h[8];
#pragma unroll
  for (int j = 0; j < 8; ++j) h[j] = hst[(bc * 16 + soff + j) * 256 + d];
  for (int ll = 0; ll < CH; ++ll) {
    const int m = base + ll;
    float dtv = bf2f(dtb[m * 256 + d]);
    float uv  = bf2f(ub[m * 256 + d]);
    float Bv[8], Cv[8];
    *(float4*)&Bv[0] = *(const float4*)&Bb[m * 16 + soff];
    *(float4*)&Bv[4] = *(const float4*)&Bb[m * 16 + soff + 4];
    *(float4*)&Cv[0] = *(const float4*)&Cb[m * 16 + soff];
    *(float4*)&Cv[4] = *(const float4*)&Cb[m * 16 + soff + 4];
    float du = dtv * uv;
    float y = 0.f;
    if (fast) {
      float e1 = __expf(-dtv);
      float e2 = e1 * e1, e4 = e2 * e2, e8 = e4 * e4;
      float dA = sh ? e8 * e1 : e1;
#pragma unroll
      for (int j = 0; j < 8; ++j) {
        h[j] = fmaf(dA, h[j], du * Bv[j]);
        y = fmaf(h[j], Cv[j], y);
        dA *= e1;
      }
    } else {
#pragma unroll
      for (int j = 0; j < 8; ++j) {
        float dA = __expf(dtv * a[j]);
        h[j] = fmaf(dA, h[j], du * Bv[j]);
        y = fmaf(h[j], Cv[j], y);
      }
    }
    y += __shfl_xor(y, 32);
    if (sh == 0) {
      float zv = bf2f(zb[m * 256 + d]);
      yb[m * 256 + d] = f2bf((y + uv * dskv) * silu_f(zv));
    }
  }
}

// ---------------------------------------------------------------------------
// LayerNorm(128) + fc(128x128) + ReLU via MFMA. 64 positions/block, 256 thr.
// ---------------------------------------------------------------------------
__global__ __launch_bounds__(256)
void ln_fc_mfma(const float* __restrict__ Hin, const float* __restrict__ gamma,
                const float* __restrict__ beta, const float* __restrict__ fcw,
                float* __restrict__ out) {
  __shared__ unsigned short hnb[64 * 136];
  __shared__ unsigned short wb[128 * 136];
  const int t = threadIdx.x;
  const int p0 = blockIdx.x << 6;
  {
    const int r = t >> 2, qd = t & 3;
    const float* hp = &Hin[(p0 + r) * 128 + (qd << 5)];
    float v[32];
#pragma unroll
    for (int j = 0; j < 8; ++j) *(float4*)&v[j << 2] = *(const float4*)&hp[j << 2];
    float s1 = 0.f, s2 = 0.f;
#pragma unroll
    for (int j = 0; j < 32; ++j) { s1 += v[j]; s2 = fmaf(v[j], v[j], s2); }
    s1 += __shfl_xor(s1, 1); s2 += __shfl_xor(s2, 1);
    s1 += __shfl_xor(s1, 2); s2 += __shfl_xor(s2, 2);
    float mu = s1 * (1.f / DM);
    float var = s2 * (1.f / DM) - mu * mu;
    float rs = rsqrtf(var + 1e-5f);
    const float* gp = &gamma[qd << 5];
    const float* bp = &beta[qd << 5];
#pragma unroll
    for (int j = 0; j < 16; ++j) {
      float h0 = fmaf((v[2*j]   - mu) * rs, gp[2*j],   bp[2*j]);
      float h1 = fmaf((v[2*j+1] - mu) * rs, gp[2*j+1], bp[2*j+1]);
      *(unsigned int*)&hnb[r * 136 + (qd << 5) + 2*j] = f2bf2(h0, h1);
    }
  }
  for (int i = t; i < 128 * 32; i += 256) {
    int row = i >> 5, c4 = i & 31;
    float4 wv = *(const float4*)&fcw[row * 128 + (c4 << 2)];
    uint2 wp = {f2bf2(wv.x, wv.y), f2bf2(wv.z, wv.w)};
    *(uint2*)&wb[row * 136 + (c4 << 2)] = wp;
  }
  __syncthreads();
  const int w = t >> 6, l = t & 63, q = l >> 4, col = l & 15;
  ffrag acc[8] = {{0.f,0.f,0.f,0.f},{0.f,0.f,0.f,0.f},{0.f,0.f,0.f,0.f},{0.f,0.f,0.f,0.f},
                  {0.f,0.f,0.f,0.f},{0.f,0.f,0.f,0.f},{0.f,0.f,0.f,0.f},{0.f,0.f,0.f,0.f}};
#pragma unroll
  for (int s = 0; s < 4; ++s) {
    int k0 = s * 32 + q * 8;
    bfrag af = *(const bfrag*)&hnb[((w << 4) + col) * 136 + k0];
#pragma unroll
    for (int nt = 0; nt < 8; ++nt) {
      bfrag bf_ = *(const bfrag*)&wb[((nt << 4) + col) * 136 + k0];
      acc[nt] = __builtin_amdgcn_mfma_f32_16x16x32_bf16(af, bf_, acc[nt], 0, 0, 0);
    }
  }
#pragma unroll
  for (int nt = 0; nt < 8; ++nt)
#pragma unroll
    for (int i = 0; i < 4; ++i) {
      int ml = (w << 4) + (q << 2) + i;
      out[(p0 + ml) * 128 + (nt << 4) + col] = fmaxf(acc[nt][i], 0.f);
    }
}

extern "C" void kernel_launch(void* const* d_in, const int* in_sizes, int n_in,
                              void* d_out, int out_size, void* d_ws, size_t ws_size,
                              hipStream_t stream) {
  (void)in_sizes; (void)n_in; (void)out_size; (void)ws_size;
  const float* s    = (const float*)d_in[0];
  const float* w_in = (const float*)d_in[1];
  const float* cw   = (const float*)d_in[2];
  const float* cb   = (const float*)d_in[3];
  const float* xw   = (const float*)d_in[4];
  const float* dtw  = (const float*)d_in[5];
  const float* dtpb = (const float*)d_in[6];
  const float* alog = (const float*)d_in[7];
  const float* dsk  = (const float*)d_in[8];
  const float* ow   = (const float*)d_in[9];
  const float* gam  = (const float*)d_in[10];
  const float* bet  = (const float*)d_in[11];
  const float* fcw  = (const float*)d_in[12];
  float* out = (float*)d_out;
  float* ws  = (float*)d_ws;

  float*          xq   = ws;                                  // M*256 f32
  unsigned short* zb   = (unsigned short*)(ws + 8388608);     // M*256 bf16
  unsigned short* ub   = (unsigned short*)(ws + 12582912);    // M*256 bf16
  unsigned short* dtb  = (unsigned short*)(ws + 16777216);    // M*256 bf16
  float*          Bb   = ws + 20971520;                       // M*16 f32
  float*          Cb   = ws + 21495808;                       // M*16 f32
  float*          cP   = ws + 22020096;                       // B*NC*4096 (later h_start)
  float*          cHe  = ws + 26214400;                       // B*NC*4096
  unsigned short* yb   = (unsigned short*)(ws + 30408704);    // M*256 bf16
  float*          hmid = ws + 34603008;                       // M*128 f32

  // 1. in_proj (bf16 MFMA): x-half -> xq f32, z-half -> zb bf16
  gemm_bf16_in<<<dim3(8, 512), 256, 0, stream>>>(s, w_in, xq, zb);
  // 2. fused conv/silu + x_proj (MFMA) + dt_proj; emits ub/dtb bf16
  xproj_dtproj<<<512, 512, 0, stream>>>(xq, xw, dtw, dtpb, cw, cb, Bb, Cb, ub, dtb);
  // 3-5. chunked selective scan
  scan_phase1<<<B_ * NC, 512, 0, stream>>>(ub, dtb, Bb, alog, cP, cHe);
  scan_combine<<<128, 256, 0, stream>>>(cP, cHe);
  scan_phase3<<<B_ * NC, 512, 0, stream>>>(ub, dtb, Bb, Cb, alog, cP, dsk, zb, yb);
  // 6. out_proj (bf16 MFMA) from yb
  gemm_bf16_out<<<dim3(2, 512), 256, 0, stream>>>(yb, ow, hmid);
  // 7. LayerNorm + fc + ReLU (bf16 MFMA)
  ln_fc_mfma<<<512, 256, 0, stream>>>(hmid, gam, bet, fcw, out);
}

// Round 9
// 274.998 us; speedup vs baseline: 1.8445x; 1.0152x over previous
//
#include <hip/hip_runtime.h>
#include <math.h>

#define B_ 8
#define L_ 4096
#define DM 128
#define DI 256
#define DSN 16
#define RK 8
#define M_ (B_*L_)      // 32768 positions
#define NC 128          // number of scan chunks
#define CH 32           // chunk length (NC*CH == L_)

typedef __attribute__((ext_vector_type(8))) short bfrag;   // 8 bf16 (4 VGPRs)
typedef __attribute__((ext_vector_type(4))) float ffrag;   // 4 fp32 acc
typedef __attribute__((ext_vector_type(2))) float f32x2;   // packed-math pair

__device__ __forceinline__ float silu_f(float x) { return x / (1.f + __expf(-x)); }

__device__ __forceinline__ unsigned short f2bf(float f) {
  unsigned int u = __builtin_bit_cast(unsigned int, f);
  unsigned int r = (u + 0x7FFFu + ((u >> 16) & 1u)) >> 16;   // RNE
  return (unsigned short)r;
}
__device__ __forceinline__ unsigned int f2bf2(float lo, float hi) {
  return (unsigned int)f2bf(lo) | ((unsigned int)f2bf(hi) << 16);
}
__device__ __forceinline__ float bf2f(unsigned int us) {
  return __builtin_bit_cast(float, us << 16);
}

// ---------------------------------------------------------------------------
// in_proj bf16 MFMA GEMM. Outputs split: x-half -> xq (f32, M x 256),
// z-half -> zb (bf16, M x 256). K=128, 64x64 tile, 256 threads.
// ---------------------------------------------------------------------------
__global__ __launch_bounds__(256)
void gemm_bf16_in(const float* __restrict__ A, const float* __restrict__ W,
                  float* __restrict__ xq, unsigned short* __restrict__ zb) {
  __shared__ unsigned short As[64 * 136];
  __shared__ unsigned short Ws[64 * 136];
  const int t = threadIdx.x;
  const int m0 = blockIdx.y << 6, n0 = blockIdx.x << 6;
  for (int i = t; i < 64 * 32; i += 256) {
    int row = i >> 5, c4 = i & 31;
    float4 av = *(const float4*)&A[(m0 + row) * 128 + (c4 << 2)];
    float4 wv = *(const float4*)&W[(n0 + row) * 128 + (c4 << 2)];
    uint2 ap = {f2bf2(av.x, av.y), f2bf2(av.z, av.w)};
    uint2 wp = {f2bf2(wv.x, wv.y), f2bf2(wv.z, wv.w)};
    *(uint2*)&As[row * 136 + (c4 << 2)] = ap;
    *(uint2*)&Ws[row * 136 + (c4 << 2)] = wp;
  }
  __syncthreads();
  const int w = t >> 6, l = t & 63, q = l >> 4, col = l & 15;
  ffrag acc[4] = {{0.f,0.f,0.f,0.f},{0.f,0.f,0.f,0.f},{0.f,0.f,0.f,0.f},{0.f,0.f,0.f,0.f}};
#pragma unroll
  for (int s = 0; s < 4; ++s) {
    int k0 = s * 32 + q * 8;
    bfrag af = *(const bfrag*)&As[((w << 4) + col) * 136 + k0];
#pragma unroll
    for (int nt = 0; nt < 4; ++nt) {
      bfrag bf_ = *(const bfrag*)&Ws[((nt << 4) + col) * 136 + k0];
      acc[nt] = __builtin_amdgcn_mfma_f32_16x16x32_bf16(af, bf_, acc[nt], 0, 0, 0);
    }
  }
#pragma unroll
  for (int nt = 0; nt < 4; ++nt)
#pragma unroll
    for (int i = 0; i < 4; ++i) {
      int ml = (w << 4) + (q << 2) + i;
      int n = n0 + (nt << 4) + col;
      int m = m0 + ml;
      if (n < 256) xq[m * 256 + n] = acc[nt][i];
      else         zb[m * 256 + (n - 256)] = f2bf(acc[nt][i]);
    }
}

// ---------------------------------------------------------------------------
// out_proj bf16 MFMA GEMM: A = yb (bf16, M x 256), W f32 (128 x 256), K=256.
// ---------------------------------------------------------------------------
__global__ __launch_bounds__(256)
void gemm_bf16_out(const unsigned short* __restrict__ Ab, const float* __restrict__ W,
                   float* __restrict__ C) {
  __shared__ unsigned short As[64 * 264];
  __shared__ unsigned short Ws[64 * 264];
  const int t = threadIdx.x;
  const int m0 = blockIdx.y << 6, n0 = blockIdx.x << 6;
  for (int i = t; i < 64 * 32; i += 256) {
    int row = i >> 5, c8 = i & 31;
    uint4 av = *(const uint4*)&Ab[(m0 + row) * 256 + (c8 << 3)];
    *(uint4*)&As[row * 264 + (c8 << 3)] = av;
  }
  for (int i = t; i < 64 * 64; i += 256) {
    int row = i >> 6, c4 = i & 63;
    float4 wv = *(const float4*)&W[(n0 + row) * 256 + (c4 << 2)];
    uint2 wp = {f2bf2(wv.x, wv.y), f2bf2(wv.z, wv.w)};
    *(uint2*)&Ws[row * 264 + (c4 << 2)] = wp;
  }
  __syncthreads();
  const int w = t >> 6, l = t & 63, q = l >> 4, col = l & 15;
  ffrag acc[4] = {{0.f,0.f,0.f,0.f},{0.f,0.f,0.f,0.f},{0.f,0.f,0.f,0.f},{0.f,0.f,0.f,0.f}};
#pragma unroll
  for (int s = 0; s < 8; ++s) {
    int k0 = s * 32 + q * 8;
    bfrag af = *(const bfrag*)&As[((w << 4) + col) * 264 + k0];
#pragma unroll
    for (int nt = 0; nt < 4; ++nt) {
      bfrag bf_ = *(const bfrag*)&Ws[((nt << 4) + col) * 264 + k0];
      acc[nt] = __builtin_amdgcn_mfma_f32_16x16x32_bf16(af, bf_, acc[nt], 0, 0, 0);
    }
  }
#pragma unroll
  for (int nt = 0; nt < 4; ++nt)
#pragma unroll
    for (int i = 0; i < 4; ++i) {
      int ml = (w << 4) + (q << 2) + i;
      C[(m0 + ml) * 128 + n0 + (nt << 4) + col] = acc[nt][i];
    }
}

// ---------------------------------------------------------------------------
// Fused conv(4)+SiLU -> bf16 LDS -> MFMA x_proj -> dt_proj + softplus.
// Emits Bb/Cb f32 and the fused udt stream (lo = u bf16, hi = dt bf16).
// ---------------------------------------------------------------------------
__global__ __launch_bounds__(512)
void xproj_dtproj(const float* __restrict__ xq, const float* __restrict__ xw,
                  const float* __restrict__ dtw, const float* __restrict__ dtpb,
                  const float* __restrict__ cw, const float* __restrict__ cb,
                  float* __restrict__ Bb, float* __restrict__ Cb,
                  unsigned int* __restrict__ udt) {
  __shared__ unsigned short ua[64 * 264];   // u bf16
  __shared__ unsigned short wb[48 * 264];   // xw bf16; rows 40..47 zeroed
  __shared__ float dtr_s[64 * 12];
  const int t = threadIdx.x;
  const int p0 = blockIdx.x << 6;
  {
    const int k = t & 255, half = t >> 8;
    const int pstart = half << 5;
    const int base = p0 + pstart;
    const int lb = base & (L_ - 1);
    const float w0 = cw[k*4], w1 = cw[k*4+1], w2 = cw[k*4+2], w3 = cw[k*4+3];
    const float bias = cb[k];
    float x0 = (lb >= 3) ? xq[(base - 3) * 256 + k] : 0.f;
    float x1 = (lb >= 2) ? xq[(base - 2) * 256 + k] : 0.f;
    float x2 = (lb >= 1) ? xq[(base - 1) * 256 + k] : 0.f;
#pragma unroll 8
    for (int it = 0; it < 32; ++it) {
      float x3 = xq[(base + it) * 256 + k];
      float u = silu_f(fmaf(w0, x0, fmaf(w1, x1, fmaf(w2, x2, fmaf(w3, x3, bias)))));
      ua[(pstart + it) * 264 + k] = f2bf(u);
      x0 = x1; x1 = x2; x2 = x3;
    }
  }
  for (int i = t; i < 40 * 256; i += 512) {
    int n = i >> 8, k = i & 255;
    wb[n * 264 + k] = f2bf(xw[i]);
  }
  for (int i = t; i < 8 * 264; i += 512) wb[40 * 264 + i] = 0;
  __syncthreads();
  const int w = t >> 6, l = t & 63, q = l >> 4, col = l & 15;
  for (int tile = w; tile < 12; tile += 8) {
    const int mt = tile & 3, nt = tile >> 2;
    ffrag acc = {0.f, 0.f, 0.f, 0.f};
#pragma unroll
    for (int s = 0; s < 8; ++s) {
      int k0 = s * 32 + q * 8;
      bfrag af = *(const bfrag*)&ua[((mt << 4) + col) * 264 + k0];
      bfrag bf_ = *(const bfrag*)&wb[((nt << 4) + col) * 264 + k0];
      acc = __builtin_amdgcn_mfma_f32_16x16x32_bf16(af, bf_, acc, 0, 0, 0);
    }
#pragma unroll
    for (int i = 0; i < 4; ++i) {
      int ml = (mt << 4) + (q << 2) + i;
      int m = p0 + ml;
      if (nt == 0) {
        if (col < 8) dtr_s[ml * 12 + col] = acc[i];
        else         Bb[m * 16 + (col - 8)] = acc[i];
      } else if (nt == 1) {
        if (col < 8) Bb[m * 16 + 8 + col] = acc[i];
        else         Cb[m * 16 + (col - 8)] = acc[i];
      } else {
        if (col < 8) Cb[m * 16 + 8 + col] = acc[i];
      }
    }
  }
  __syncthreads();
  {
    const int d = t & 255, half = t >> 8;
    const int pstart = half << 5;
    float w8[8];
    *(float4*)&w8[0] = *(const float4*)&dtw[d * 8];
    *(float4*)&w8[4] = *(const float4*)&dtw[d * 8 + 4];
    const float bias = dtpb[d];
#pragma unroll 4
    for (int pp = pstart; pp < pstart + 32; ++pp) {
      float r0[8];
      *(float4*)&r0[0] = *(const float4*)&dtr_s[pp * 12];
      *(float4*)&r0[4] = *(const float4*)&dtr_s[pp * 12 + 4];
      float a2 = bias;
#pragma unroll
      for (int r2 = 0; r2 < 8; ++r2) a2 = fmaf(r0[r2], w8[r2], a2);
      float sp = (a2 > 20.f) ? a2 : log1pf(__expf(a2));
      udt[(p0 + pp) * 256 + d] =
          (unsigned int)ua[pp * 264 + d] | ((unsigned int)f2bf(sp) << 16);
    }
  }
}

// ---------------------------------------------------------------------------
// Scan phase 1: 512 threads; thread = (channel, state-half), h as f32x2[4]
// (packed v_pk_fma_f32). P via exp(a*sum(dt)). Fast path: dA powers of e1.
// ---------------------------------------------------------------------------
__global__ __launch_bounds__(512, 4)
void scan_phase1(const unsigned int* __restrict__ udt,
                 const float* __restrict__ Bb, const float* __restrict__ alog,
                 float* __restrict__ cP, float* __restrict__ cHe) {
  const int bc = blockIdx.x;
  const int b = bc >> 7, c = bc & (NC - 1);
  const int t = threadIdx.x;
  const int l = t & 63, w = t >> 6;
  const int d = (w << 5) + (l & 31);
  const int sh = l >> 5;
  const int soff = sh << 3;
  const int base = b * L_ + c * CH;
  float a[8];
  bool okl = true;
#pragma unroll
  for (int j = 0; j < 8; ++j) {
    a[j] = -__expf(alog[d * 16 + soff + j]);
    float tgt = (float)(soff + j + 1);
    okl = okl && (fabsf(a[j] + tgt) <= 1e-3f * tgt);
  }
  const bool fast = (bool)__all((int)okl);
  f32x2 h2[4] = {{0.f,0.f},{0.f,0.f},{0.f,0.f},{0.f,0.f}};
  float sdt = 0.f;
  for (int ll = 0; ll < CH; ++ll) {
    const int m = base + ll;
    unsigned int wv = udt[m * 256 + d];
    float uv  = bf2f(wv & 0xFFFFu);
    float dtv = bf2f(wv >> 16);
    float4 b0 = *(const float4*)&Bb[m * 16 + soff];
    float4 b1 = *(const float4*)&Bb[m * 16 + soff + 4];
    f32x2 B2[4] = {{b0.x,b0.y},{b0.z,b0.w},{b1.x,b1.y},{b1.z,b1.w}};
    float du = dtv * uv;
    sdt += dtv;
    if (fast) {
      float e1 = __expf(-dtv);
      float e2 = e1 * e1, e4 = e2 * e2, e8 = e4 * e4;
      float st = sh ? e8 * e1 : e1;
      f32x2 dA = {st, st * e1};
      f32x2 e22 = {e2, e2};
      f32x2 du2 = {du, du};
#pragma unroll
      for (int j = 0; j < 4; ++j) {
        h2[j] = dA * h2[j] + du2 * B2[j];
        dA = dA * e22;
      }
    } else {
#pragma unroll
      for (int j = 0; j < 8; ++j) {
        float dA = __expf(dtv * a[j]);
        h2[j >> 1][j & 1] = fmaf(dA, h2[j >> 1][j & 1], du * B2[j >> 1][j & 1]);
      }
    }
  }
#pragma unroll
  for (int j = 0; j < 8; ++j) {
    int o = (bc * 16 + soff + j) * 256 + d;
    cP[o]  = __expf(a[j] * sdt);
    cHe[o] = h2[j >> 1][j & 1];
  }
}

// ---------------------------------------------------------------------------
// Scan phase 2: serial stitch over chunks; h_start overwrites cP in place.
// ---------------------------------------------------------------------------
__global__ __launch_bounds__(256)
void scan_combine(float* __restrict__ cP, const float* __restrict__ cHe) {
  int tid = blockIdx.x * 256 + threadIdx.x;   // < 8*4096
  int b = tid >> 12;
  int sd = tid & 4095;
  float hs = 0.f;
  for (int c = 0; c < NC; ++c) {
    int idx = (b * NC + c) * 4096 + sd;
    float p = cP[idx];
    float he = cHe[idx];
    cP[idx] = hs;
    hs = fmaf(p, hs, he);
  }
}

// ---------------------------------------------------------------------------
// Scan phase 3: replay from h_start (packed math); y via pk_fma + horizontal
// + shfl_xor(32); gated output written bf16 to yb.
// ---------------------------------------------------------------------------
__global__ __launch_bounds__(512, 4)
void scan_phase3(const unsigned int* __restrict__ udt,
                 const float* __restrict__ Bb, const float* __restrict__ Cb,
                 const float* __restrict__ alog, const float* __restrict__ hst,
                 const float* __restrict__ dsk,
                 const unsigned short* __restrict__ zb,
                 unsigned short* __restrict__ yb) {
  const int bc = blockIdx.x;
  const int b = bc >> 7, c = bc & (NC - 1);
  const int t = threadIdx.x;
  const int l = t & 63, w = t >> 6;
  const int d = (w << 5) + (l & 31);
  const int sh = l >> 5;
  const int soff = sh << 3;
  const int base = b * L_ + c * CH;
  float a[8];
  bool okl = true;
#pragma unroll
  for (int j = 0; j < 8; ++j) {
    a[j] = -__expf(alog[d * 16 + soff + j]);
    float tgt = (float)(soff + j + 1);
    okl = okl && (fabsf(a[j] + tgt) <= 1e-3f * tgt);
  }
  const bool fast = (bool)__all((int)okl);
  const float dskv = dsk[d];
  f32x2 h2[4];
#pragma unroll
  for (int j = 0; j < 8; ++j) h2[j >> 1][j & 1] = hst[(bc * 16 + soff + j) * 256 + d];
  for (int ll = 0; ll < CH; ++ll) {
    const int m = base + ll;
    unsigned int wv = udt[m * 256 + d];
    float uv  = bf2f(wv & 0xFFFFu);
    float dtv = bf2f(wv >> 16);
    float4 b0 = *(const float4*)&Bb[m * 16 + soff];
    float4 b1 = *(const float4*)&Bb[m * 16 + soff + 4];
    float4 c0 = *(const float4*)&Cb[m * 16 + soff];
    float4 c1 = *(const float4*)&Cb[m * 16 + soff + 4];
    f32x2 B2[4] = {{b0.x,b0.y},{b0.z,b0.w},{b1.x,b1.y},{b1.z,b1.w}};
    f32x2 C2[4] = {{c0.x,c0.y},{c0.z,c0.w},{c1.x,c1.y},{c1.z,c1.w}};
    float du = dtv * uv;
    f32x2 y2 = {0.f, 0.f};
    if (fast) {
      float e1 = __expf(-dtv);
      float e2 = e1 * e1, e4 = e2 * e2, e8 = e4 * e4;
      float st = sh ? e8 * e1 : e1;
      f32x2 dA = {st, st * e1};
      f32x2 e22 = {e2, e2};
      f32x2 du2 = {du, du};
#pragma unroll
      for (int j = 0; j < 4; ++j) {
        h2[j] = dA * h2[j] + du2 * B2[j];
        y2 = y2 + h2[j] * C2[j];
        dA = dA * e22;
      }
    } else {
#pragma unroll
      for (int j = 0; j < 8; ++j) {
        float dA = __expf(dtv * a[j]);
        float hh = fmaf(dA, h2[j >> 1][j & 1], du * B2[j >> 1][j & 1]);
        h2[j >> 1][j & 1] = hh;
        y2[j & 1] = fmaf(hh, C2[j >> 1][j & 1], y2[j & 1]);
      }
    }
    float y = y2.x + y2.y;
    y += __shfl_xor(y, 32);
    if (sh == 0) {
      float zv = bf2f((unsigned int)zb[m * 256 + d]);
      yb[m * 256 + d] = f2bf((y + uv * dskv) * silu_f(zv));
    }
  }
}

// ---------------------------------------------------------------------------
// LayerNorm(128) + fc(128x128) + ReLU via MFMA. 64 positions/block, 256 thr.
// ---------------------------------------------------------------------------
__global__ __launch_bounds__(256)
void ln_fc_mfma(const float* __restrict__ Hin, const float* __restrict__ gamma,
                const float* __restrict__ beta, const float* __restrict__ fcw,
                float* __restrict__ out) {
  __shared__ unsigned short hnb[64 * 136];
  __shared__ unsigned short wb[128 * 136];
  const int t = threadIdx.x;
  const int p0 = blockIdx.x << 6;
  {
    const int r = t >> 2, qd = t & 3;
    const float* hp = &Hin[(p0 + r) * 128 + (qd << 5)];
    float v[32];
#pragma unroll
    for (int j = 0; j < 8; ++j) *(float4*)&v[j << 2] = *(const float4*)&hp[j << 2];
    float s1 = 0.f, s2 = 0.f;
#pragma unroll
    for (int j = 0; j < 32; ++j) { s1 += v[j]; s2 = fmaf(v[j], v[j], s2); }
    s1 += __shfl_xor(s1, 1); s2 += __shfl_xor(s2, 1);
    s1 += __shfl_xor(s1, 2); s2 += __shfl_xor(s2, 2);
    float mu = s1 * (1.f / DM);
    float var = s2 * (1.f / DM) - mu * mu;
    float rs = rsqrtf(var + 1e-5f);
    const float* gp = &gamma[qd << 5];
    const float* bp = &beta[qd << 5];
#pragma unroll
    for (int j = 0; j < 16; ++j) {
      float h0 = fmaf((v[2*j]   - mu) * rs, gp[2*j],   bp[2*j]);
      float h1 = fmaf((v[2*j+1] - mu) * rs, gp[2*j+1], bp[2*j+1]);
      *(unsigned int*)&hnb[r * 136 + (qd << 5) + 2*j] = f2bf2(h0, h1);
    }
  }
  for (int i = t; i < 128 * 32; i += 256) {
    int row = i >> 5, c4 = i & 31;
    float4 wv = *(const float4*)&fcw[row * 128 + (c4 << 2)];
    uint2 wp = {f2bf2(wv.x, wv.y), f2bf2(wv.z, wv.w)};
    *(uint2*)&wb[row * 136 + (c4 << 2)] = wp;
  }
  __syncthreads();
  const int w = t >> 6, l = t & 63, q = l >> 4, col = l & 15;
  ffrag acc[8] = {{0.f,0.f,0.f,0.f},{0.f,0.f,0.f,0.f},{0.f,0.f,0.f,0.f},{0.f,0.f,0.f,0.f},
                  {0.f,0.f,0.f,0.f},{0.f,0.f,0.f,0.f},{0.f,0.f,0.f,0.f},{0.f,0.f,0.f,0.f}};
#pragma unroll
  for (int s = 0; s < 4; ++s) {
    int k0 = s * 32 + q * 8;
    bfrag af = *(const bfrag*)&hnb[((w << 4) + col) * 136 + k0];
#pragma unroll
    for (int nt = 0; nt < 8; ++nt) {
      bfrag bf_ = *(const bfrag*)&wb[((nt << 4) + col) * 136 + k0];
      acc[nt] = __builtin_amdgcn_mfma_f32_16x16x32_bf16(af, bf_, acc[nt], 0, 0, 0);
    }
  }
#pragma unroll
  for (int nt = 0; nt < 8; ++nt)
#pragma unroll
    for (int i = 0; i < 4; ++i) {
      int ml = (w << 4) + (q << 2) + i;
      out[(p0 + ml) * 128 + (nt << 4) + col] = fmaxf(acc[nt][i], 0.f);
    }
}

extern "C" void kernel_launch(void* const* d_in, const int* in_sizes, int n_in,
                              void* d_out, int out_size, void* d_ws, size_t ws_size,
                              hipStream_t stream) {
  (void)in_sizes; (void)n_in; (void)out_size; (void)ws_size;
  const float* s    = (const float*)d_in[0];
  const float* w_in = (const float*)d_in[1];
  const float* cw   = (const float*)d_in[2];
  const float* cb   = (const float*)d_in[3];
  const float* xw   = (const float*)d_in[4];
  const float* dtw  = (const float*)d_in[5];
  const float* dtpb = (const float*)d_in[6];
  const float* alog = (const float*)d_in[7];
  const float* dsk  = (const float*)d_in[8];
  const float* ow   = (const float*)d_in[9];
  const float* gam  = (const float*)d_in[10];
  const float* bet  = (const float*)d_in[11];
  const float* fcw  = (const float*)d_in[12];
  float* out = (float*)d_out;
  float* ws  = (float*)d_ws;

  float*          xq   = ws;                                  // M*256 f32
  unsigned short* zb   = (unsigned short*)(ws + 8388608);     // M*256 bf16
  unsigned int*   udt  = (unsigned int*)(ws + 12582912);      // M*256 (u|dt bf16 pair)
  float*          Bb   = ws + 20971520;                       // M*16 f32
  float*          Cb   = ws + 21495808;                       // M*16 f32
  float*          cP   = ws + 22020096;                       // B*NC*4096 (later h_start)
  float*          cHe  = ws + 26214400;                       // B*NC*4096
  unsigned short* yb   = (unsigned short*)(ws + 30408704);    // M*256 bf16
  float*          hmid = ws + 34603008;                       // M*128 f32

  // 1. in_proj (bf16 MFMA): x-half -> xq f32, z-half -> zb bf16
  gemm_bf16_in<<<dim3(8, 512), 256, 0, stream>>>(s, w_in, xq, zb);
  // 2. fused conv/silu + x_proj (MFMA) + dt_proj; emits fused udt stream
  xproj_dtproj<<<512, 512, 0, stream>>>(xq, xw, dtw, dtpb, cw, cb, Bb, Cb, udt);
  // 3-5. chunked selective scan (packed f32 math)
  scan_phase1<<<B_ * NC, 512, 0, stream>>>(udt, Bb, alog, cP, cHe);
  scan_combine<<<128, 256, 0, stream>>>(cP, cHe);
  scan_phase3<<<B_ * NC, 512, 0, stream>>>(udt, Bb, Cb, alog, cP, dsk, zb, yb);
  // 6. out_proj (bf16 MFMA) from yb
  gemm_bf16_out<<<dim3(2, 512), 256, 0, stream>>>(yb, ow, hmid);
  // 7. LayerNorm + fc + ReLU (bf16 MFMA)
  ln_fc_mfma<<<512, 256, 0, stream>>>(hmid, gam, bet, fcw, out);
}